// Round 2
// baseline (4842.860 us; speedup 1.0000x reference)
//
#include <hip/hip_runtime.h>
#include <math.h>

// ---------------------------------------------------------------------------
// GlobalSceneEncoder: 4-stage point-transformer encoder, fp32, f64 selections.
// B=4, N0=4096, D=384, K=16.
// ---------------------------------------------------------------------------

// ---------------- split pts -> pos0, x0 ----------------
__global__ __launch_bounds__(128) void split_kernel(
    const float* __restrict__ pts, float* __restrict__ pos0, float* __restrict__ x0)
{
  const int n = blockIdx.x;
  const int b = blockIdx.y;
  const float* src = pts + ((long)b * 4096 + n) * 387;
  float* pd = pos0 + ((long)b * 4096 + n) * 3;
  float* xd = x0 + ((long)b * 4096 + n) * 384;
  for (int e = threadIdx.x; e < 387; e += 128) {
    float v = src[e];
    if (e < 3) pd[e] = v; else xd[e - 3] = v;
  }
}

// ---------------- FPS: one block per batch, sequential M-1 steps -----------
// One barrier per step: per-wave butterfly -> wave winners in LDS (double-
// buffered by parity) -> barrier -> every thread serially scans the <=16
// winners (broadcast LDS reads). Positions cached in LDS for q lookup.
template<int NPTS, int NTHR>
__global__ __launch_bounds__(NTHR) void fps_kernel(
    const float* __restrict__ pos,
    int* __restrict__ idx_out, float* __restrict__ pos_out)
{
  constexpr int NPT = NPTS / NTHR;   // points per thread
  constexpr int NW = NTHR / 64;      // waves per block
  constexpr int M = NPTS / 4;
  const int b = blockIdx.x;
  pos += (long)b * NPTS * 3; idx_out += (long)b * M; pos_out += (long)b * M * 3;
  const int t = threadIdx.x;

  __shared__ float spx[NPTS], spy[NPTS], spz[NPTS];
  __shared__ double s_val[2][NW > 1 ? NW : 1];
  __shared__ int s_idx[2][NW > 1 ? NW : 1];

  float px[NPT], py[NPT], pz[NPT];
  double dmin[NPT];
  #pragma unroll
  for (int i = 0; i < NPT; i++) {
    const int j = i * NTHR + t;
    px[i] = pos[j*3]; py[i] = pos[j*3+1]; pz[i] = pos[j*3+2];
    spx[j] = px[i]; spy[j] = py[i]; spz[j] = pz[i];
  }
  const float sxf = pos[0], syf = pos[1], szf = pos[2];
  {
    const double sx = sxf, sy = syf, sz = szf;
    #pragma unroll
    for (int i = 0; i < NPT; i++) {
      double dx = (double)px[i]-sx, dy = (double)py[i]-sy, dz = (double)pz[i]-sz;
      dmin[i] = dx*dx + dy*dy + dz*dz;
    }
  }
  if (t == 0) { idx_out[0] = 0; pos_out[0] = sxf; pos_out[1] = syf; pos_out[2] = szf; }
  if (NW > 1) __syncthreads();   // spx/spy/spz visible

  for (int m = 1; m < M; ++m) {
    // thread-local argmax
    double best = -1.0; int bj = 0x7fffffff;
    #pragma unroll
    for (int i = 0; i < NPT; i++)
      if (dmin[i] > best) { best = dmin[i]; bj = i * NTHR + t; }
    // wave butterfly (keeps winner in all lanes)
    #pragma unroll
    for (int off = 32; off; off >>= 1) {
      double ov = __shfl_xor(best, off); int oj = __shfl_xor(bj, off);
      if (ov > best || (ov == best && oj < bj)) { best = ov; bj = oj; }
    }
    int sel;
    if (NW > 1) {
      const int p = m & 1;
      if ((t & 63) == 0) { s_val[p][t >> 6] = best; s_idx[p][t >> 6] = bj; }
      __syncthreads();
      double gb = s_val[p][0]; int gj = s_idx[p][0];
      #pragma unroll
      for (int w = 1; w < NW; w++) {
        const double ov = s_val[p][w]; const int oj = s_idx[p][w];
        if (ov > gb || (ov == gb && oj < gj)) { gb = ov; gj = oj; }
      }
      sel = gj;
    } else {
      sel = bj;
    }
    const float qxf = spx[sel], qyf = spy[sel], qzf = spz[sel];
    const double qx = qxf, qy = qyf, qz = qzf;
    #pragma unroll
    for (int i = 0; i < NPT; i++) {
      double dx = (double)px[i]-qx, dy = (double)py[i]-qy, dz = (double)pz[i]-qz;
      double dd = dx*dx + dy*dy + dz*dz;
      if (dd < dmin[i]) dmin[i] = dd;
    }
    if (t == 0) { idx_out[m] = sel; pos_out[m*3] = qxf; pos_out[m*3+1] = qyf; pos_out[m*3+2] = qzf; }
  }
}

// ---------------- KNN: one wave per query, 16 lexicographic-min passes -----
template<int C>
__global__ __launch_bounds__(64) void knn_kernel(
    const float* __restrict__ pos, const float* __restrict__ qpos,
    int N, int M, int* __restrict__ nbr, float* __restrict__ vld, double r2)
{
  const int m = blockIdx.x, b = blockIdx.y;
  pos += (long)b * N * 3; qpos += (long)b * M * 3;
  nbr += (long)b * (1024 * 16); vld += (long)b * (1024 * 16);
  const int lane = threadIdx.x;
  const double qx = qpos[m*3], qy = qpos[m*3+1], qz = qpos[m*3+2];
  double d[C];
  #pragma unroll
  for (int c = 0; c < C; c++) {
    const int j = c * 64 + lane;
    double dx = (double)pos[j*3] - qx;
    double dy = (double)pos[j*3+1] - qy;
    double dz = (double)pos[j*3+2] - qz;
    d[c] = dx*dx + dy*dy + dz*dz;
  }
  double pd = -1.0; int pj = -1;
  for (int k = 0; k < 16; k++) {
    double best = 1e300; int bj = 0x7fffffff;
    #pragma unroll
    for (int c = 0; c < C; c++) {
      const int j = c * 64 + lane;
      const bool after = (d[c] > pd) || (d[c] == pd && j > pj);
      if (after && d[c] < best) { best = d[c]; bj = j; }
    }
    #pragma unroll
    for (int off = 32; off; off >>= 1) {
      double ov = __shfl_xor(best, off); int oj = __shfl_xor(bj, off);
      if (ov < best || (ov == best && oj < bj)) { best = ov; bj = oj; }
    }
    pd = best; pj = bj;
    if (lane == 0) { nbr[m*16+k] = bj; vld[m*16+k] = (best <= r2) ? 1.0f : 0.0f; }
  }
}

// ---------------- fp32 tiled GEMM, 64x64x16, 3 A-operand modes -------------
// AMODE 0: A = rows of p.A (optional gather)     -> v / a_src / a_dst
// AMODE 1: A = relu(rel @ pw1 + pb1) on the fly  -> delta GEMM
// AMODE 2: A = a_dst[m] - a_src[nbr] + delta     -> alpha GEMM
struct GemmP {
  const float* A; long sA;
  const float* W;
  const float* bias;
  float* C; long sC;
  int R;
  const int* gather; long sG;
  const float* qpos; long sQ;
  const float* pos;  long sP;
  const int* nbr;    long sN;
  const float* pw1;
  const float* pb1;
  const float* adst; long sAD;
  const float* asrc; long sAS;
  int row0;
};

template<int AMODE, bool GATHER, bool BIAS, bool RELU>
__global__ __launch_bounds__(256) void gemm_kernel(GemmP p)
{
  const int b = blockIdx.z;
  const int rb = blockIdx.x * 64;
  const int cb = blockIdx.y * 64;
  const int t = threadIdx.x;
  const float* A = p.A ? (p.A + (long)b * p.sA) : nullptr;
  float* C = p.C + (long)b * p.sC;
  const int* gat = GATHER ? (p.gather + (long)b * p.sG) : nullptr;
  const int* nbrb = (AMODE != 0) ? (p.nbr + (long)b * p.sN) : nullptr;
  const float* qposb = (AMODE == 1) ? (p.qpos + (long)b * p.sQ) : nullptr;
  const float* posb  = (AMODE == 1) ? (p.pos + (long)b * p.sP) : nullptr;
  const float* adstb = (AMODE == 2) ? (p.adst + (long)b * p.sAD) : nullptr;
  const float* asrcb = (AMODE == 2) ? (p.asrc + (long)b * p.sAS) : nullptr;

  __shared__ float As[16][68];
  __shared__ float Bs[16][68];

  const int ty = t >> 4, tx = t & 15;
  float acc[4][4];
  #pragma unroll
  for (int i = 0; i < 4; i++)
    #pragma unroll
    for (int j = 0; j < 4; j++) acc[i][j] = 0.f;

  const int ar = rb + (t >> 2);
  const int acoff = (t & 3) << 2;

  for (int k0 = 0; k0 < 384; k0 += 16) {
    const int ac = k0 + acoff;
    float4 av;
    if (AMODE == 0) {
      if (ar < p.R) {
        const long src = GATHER ? (long)gat[ar] : (long)ar;
        av = *(const float4*)(A + src * 384 + ac);
      } else av = make_float4(0.f, 0.f, 0.f, 0.f);
    } else if (AMODE == 1) {
      const int grow = p.row0 + ar;
      const int mq = grow >> 4;
      const int n = nbrb[grow];
      const float rx = qposb[mq*3+0] - posb[n*3+0];
      const float ry = qposb[mq*3+1] - posb[n*3+1];
      const float rz = qposb[mq*3+2] - posb[n*3+2];
      const float4 w0 = *(const float4*)(p.pw1 + ac);
      const float4 w1 = *(const float4*)(p.pw1 + 384 + ac);
      const float4 w2 = *(const float4*)(p.pw1 + 768 + ac);
      const float4 b1 = *(const float4*)(p.pb1 + ac);
      av.x = fmaxf(rx*w0.x + ry*w1.x + rz*w2.x + b1.x, 0.f);
      av.y = fmaxf(rx*w0.y + ry*w1.y + rz*w2.y + b1.y, 0.f);
      av.z = fmaxf(rx*w0.z + ry*w1.z + rz*w2.z + b1.z, 0.f);
      av.w = fmaxf(rx*w0.w + ry*w1.w + rz*w2.w + b1.w, 0.f);
    } else {
      const int grow = p.row0 + ar;
      const int mq = grow >> 4;
      const int n = nbrb[grow];
      const float4 dd = *(const float4*)(A + (long)ar * 384 + ac);
      const float4 a4 = *(const float4*)(adstb + (long)mq * 384 + ac);
      const float4 s4 = *(const float4*)(asrcb + (long)n * 384 + ac);
      av.x = a4.x - s4.x + dd.x;
      av.y = a4.y - s4.y + dd.y;
      av.z = a4.z - s4.z + dd.z;
      av.w = a4.w - s4.w + dd.w;
    }
    As[acoff + 0][t >> 2] = av.x;
    As[acoff + 1][t >> 2] = av.y;
    As[acoff + 2][t >> 2] = av.z;
    As[acoff + 3][t >> 2] = av.w;

    const float4 wv = *(const float4*)(p.W + (long)(k0 + (t >> 4)) * 384 + cb + ((t & 15) << 2));
    *(float4*)&Bs[t >> 4][(t & 15) << 2] = wv;
    __syncthreads();

    #pragma unroll
    for (int kk = 0; kk < 16; kk++) {
      const float4 a4 = *(const float4*)&As[kk][ty << 2];
      const float4 b4 = *(const float4*)&Bs[kk][tx << 2];
      const float aa[4] = {a4.x, a4.y, a4.z, a4.w};
      const float bb[4] = {b4.x, b4.y, b4.z, b4.w};
      #pragma unroll
      for (int i = 0; i < 4; i++)
        #pragma unroll
        for (int j = 0; j < 4; j++)
          acc[i][j] = fmaf(aa[i], bb[j], acc[i][j]);
    }
    __syncthreads();
  }

  float4 bi = make_float4(0.f, 0.f, 0.f, 0.f);
  if (BIAS) bi = *(const float4*)(p.bias + cb + (tx << 2));
  #pragma unroll
  for (int i = 0; i < 4; i++) {
    const int r = rb + (ty << 2) + i;
    if (r < p.R) {
      float4 o;
      o.x = acc[i][0] + bi.x; o.y = acc[i][1] + bi.y;
      o.z = acc[i][2] + bi.z; o.w = acc[i][3] + bi.w;
      if (RELU) { o.x = fmaxf(o.x, 0.f); o.y = fmaxf(o.y, 0.f); o.z = fmaxf(o.z, 0.f); o.w = fmaxf(o.w, 0.f); }
      *(float4*)(C + (long)r * 384 + cb + (tx << 2)) = o;
    }
  }
}

// ---------------- masked softmax over K + weighted sum + LayerNorm ---------
__global__ __launch_bounds__(128) void attnln_kernel(
    const float* __restrict__ alpha, const float* __restrict__ delta,
    const float* __restrict__ vbuf, const int* __restrict__ nbr,
    const float* __restrict__ vldb, const float* __restrict__ lng,
    const float* __restrict__ lnb, float* __restrict__ xout,
    int q0, long sCh, long sV, long sNb, long sX)
{
  const int ml = blockIdx.x, b = blockIdx.y;
  const int m = q0 + ml;
  alpha += (long)b * sCh; delta += (long)b * sCh; vbuf += (long)b * sV;
  nbr += (long)b * sNb; vldb += (long)b * sNb; xout += (long)b * sX;
  const int t = threadIdx.x;

  int nb[16]; float vl[16];
  #pragma unroll
  for (int k = 0; k < 16; k++) { nb[k] = nbr[m*16+k]; vl[k] = vldb[m*16+k]; }

  const long rbase = (long)ml * 16 * 384;
  float av[16][3];
  #pragma unroll
  for (int k = 0; k < 16; k++)
    #pragma unroll
    for (int i = 0; i < 3; i++) {
      const float a = alpha[rbase + k*384 + t + i*128];
      av[k][i] = (vl[k] > 0.5f) ? a : -1e30f;
    }
  float mx[3] = {-3.4e38f, -3.4e38f, -3.4e38f};
  #pragma unroll
  for (int k = 0; k < 16; k++)
    #pragma unroll
    for (int i = 0; i < 3; i++) mx[i] = fmaxf(mx[i], av[k][i]);
  float sm[3] = {0.f, 0.f, 0.f};
  #pragma unroll
  for (int k = 0; k < 16; k++)
    #pragma unroll
    for (int i = 0; i < 3; i++) { const float e = expf(av[k][i] - mx[i]); av[k][i] = e; sm[i] += e; }
  float rs[3];
  #pragma unroll
  for (int i = 0; i < 3; i++) rs[i] = 1.0f / sm[i];
  float o[3] = {0.f, 0.f, 0.f};
  #pragma unroll
  for (int k = 0; k < 16; k++) {
    const long nrow = (long)nb[k] * 384;
    #pragma unroll
    for (int i = 0; i < 3; i++) {
      const int dd = t + i * 128;
      const float vv = vbuf[nrow + dd] + delta[rbase + k*384 + dd];
      o[i] += (av[k][i] * rs[i] * vl[k]) * vv;
    }
  }
  // LayerNorm over 384
  __shared__ float sred[2];
  float s1 = o[0] + o[1] + o[2];
  #pragma unroll
  for (int off = 32; off; off >>= 1) s1 += __shfl_xor(s1, off);
  if ((t & 63) == 0) sred[t >> 6] = s1;
  __syncthreads();
  const float mean = (sred[0] + sred[1]) * (1.0f / 384.0f);
  __syncthreads();
  float s2 = 0.f;
  #pragma unroll
  for (int i = 0; i < 3; i++) { const float dd = o[i] - mean; s2 += dd * dd; }
  #pragma unroll
  for (int off = 32; off; off >>= 1) s2 += __shfl_xor(s2, off);
  if ((t & 63) == 0) sred[t >> 6] = s2;
  __syncthreads();
  const float var = (sred[0] + sred[1]) * (1.0f / 384.0f);
  const float rstd = 1.0f / sqrtf(var + 1e-5f);
  #pragma unroll
  for (int i = 0; i < 3; i++) {
    const int dd = t + i * 128;
    xout[(long)m * 384 + dd] = (o[i] - mean) * rstd * lng[dd] + lnb[dd];
  }
}

// ---------------- final projection + LayerNorm -----------------------------
__global__ __launch_bounds__(384) void feat_kernel(
    const float* __restrict__ x4, const float* __restrict__ pw,
    const float* __restrict__ pb, const float* __restrict__ g,
    const float* __restrict__ be, float* __restrict__ outf)
{
  const int row = blockIdx.x, b = blockIdx.y;
  const long r = (long)b * 16 + row;
  const int d = threadIdx.x;
  __shared__ float xs[384];
  xs[d] = x4[r * 384 + d];
  __syncthreads();
  float acc = pb[d];
  #pragma unroll 8
  for (int j = 0; j < 384; j++) acc = fmaf(xs[j], pw[(long)j * 384 + d], acc);
  __shared__ float sred[6];
  float s = acc;
  #pragma unroll
  for (int off = 32; off; off >>= 1) s += __shfl_xor(s, off);
  if ((d & 63) == 0) sred[d >> 6] = s;
  __syncthreads();
  const float mean = (sred[0]+sred[1]+sred[2]+sred[3]+sred[4]+sred[5]) * (1.0f/384.0f);
  __syncthreads();
  float dv = (acc - mean) * (acc - mean);
  #pragma unroll
  for (int off = 32; off; off >>= 1) dv += __shfl_xor(dv, off);
  if ((d & 63) == 0) sred[d >> 6] = dv;
  __syncthreads();
  const float var = (sred[0]+sred[1]+sred[2]+sred[3]+sred[4]+sred[5]) * (1.0f/384.0f);
  const float rstd = 1.0f / sqrtf(var + 1e-5f);
  outf[r * 384 + d] = (acc - mean) * rstd * g[d] + be[d];
}

// ---------------- pos + pad outputs ----------------------------------------
__global__ void tail_kernel(const float* __restrict__ p4, float* __restrict__ out)
{
  const int t = threadIdx.x;
  if (t < 192) out[t] = p4[t];
  if (t < 64) out[192 + 24576 + t] = 0.0f;
}

// ---------------------------------------------------------------------------
extern "C" void kernel_launch(void* const* d_in, const int* in_sizes, int n_in,
                              void* d_out, int out_size, void* d_ws, size_t ws_size,
                              hipStream_t stream)
{
  (void)in_sizes; (void)n_in; (void)out_size; (void)ws_size;
  const float* pts    = (const float*)d_in[0];
  const float* lin_w  = (const float*)d_in[1];
  const float* lin_b  = (const float*)d_in[2];
  const float* src_w  = (const float*)d_in[3];
  const float* dst_w  = (const float*)d_in[4];
  const float* pos_w1 = (const float*)d_in[5];
  const float* pos_b1 = (const float*)d_in[6];
  const float* pos_w2 = (const float*)d_in[7];
  const float* pos_b2 = (const float*)d_in[8];
  const float* attn_w = (const float*)d_in[9];
  const float* attn_b = (const float*)d_in[10];
  const float* ln_g   = (const float*)d_in[11];
  const float* ln_b   = (const float*)d_in[12];
  const float* proj_w = (const float*)d_in[13];
  const float* proj_b = (const float*)d_in[14];
  const float* pln_g  = (const float*)d_in[15];
  const float* pln_b  = (const float*)d_in[16];
  float* out = (float*)d_out;

  // ---- workspace layout (floats) ----
  constexpr long SX0 = 4096L*384, SX1 = 1024L*384, SX2 = 256L*384, SX3 = 64L*384, SX4 = 16L*384;
  constexpr long SP0 = 4096L*3, SP1 = 1024L*3, SP2 = 256L*3, SP3 = 64L*3, SP4 = 16L*3;
  constexpr long SV  = 4096L*384;   // v / a_src per-batch stride
  constexpr long SAD = 1024L*384;   // a_dst per-batch stride
  constexpr long SCH = 4096L*384;   // delta/alpha chunk per-batch stride
  constexpr long SNB = 1024L*16;    // nbr / valid per-batch stride

  float* ws = (float*)d_ws;
  float* x0 = ws; ws += 4*SX0;
  float* x1 = ws; ws += 4*SX1;
  float* x2 = ws; ws += 4*SX2;
  float* x3 = ws; ws += 4*SX3;
  float* x4 = ws; ws += 4*SX4;
  float* p0 = ws; ws += 4*SP0;
  float* p1 = ws; ws += 4*SP1;
  float* p2 = ws; ws += 4*SP2;
  float* p3 = ws; ws += 4*SP3;
  float* p4 = ws; ws += 4*SP4;
  float* vb = ws; ws += 4*SV;
  float* asb = ws; ws += 4*SV;
  float* adb = ws; ws += 4*SAD;
  float* db = ws; ws += 4*SCH;
  float* ab = ws; ws += 4*SCH;
  float* vld = ws; ws += 4*SNB;
  int* nb = (int*)ws; ws += 4*SNB;
  int* ix[4];
  ix[0] = (int*)ws; ws += 4*1024;
  ix[1] = (int*)ws; ws += 4*256;
  ix[2] = (int*)ws; ws += 4*64;
  ix[3] = (int*)ws; ws += 4*16;

  const int Ns[4] = {4096, 1024, 256, 64};
  const int Ms[4] = {1024, 256, 64, 16};
  const double R2[4] = {1.0, 4.0, 16.0, 64.0};
  float* X[5] = {x0, x1, x2, x3, x4};
  float* P[5] = {p0, p1, p2, p3, p4};
  long SXs[5] = {SX0, SX1, SX2, SX3, SX4};
  long SPs[5] = {SP0, SP1, SP2, SP3, SP4};

  // split pts
  split_kernel<<<dim3(4096, 4), 128, 0, stream>>>(pts, p0, x0);

  // FPS chain (depends only on positions)
  fps_kernel<4096, 1024><<<dim3(4), 1024, 0, stream>>>(P[0], ix[0], P[1]);
  fps_kernel<1024, 1024><<<dim3(4), 1024, 0, stream>>>(P[1], ix[1], P[2]);
  fps_kernel<256, 256><<<dim3(4), 256, 0, stream>>>(P[2], ix[2], P[3]);
  fps_kernel<64, 64><<<dim3(4), 64, 0, stream>>>(P[3], ix[3], P[4]);

  for (int s = 0; s < 4; s++) {
    const int N = Ns[s], M = Ms[s];
    // KNN
    switch (s) {
      case 0: knn_kernel<64><<<dim3(M, 4), 64, 0, stream>>>(P[s], P[s+1], N, M, nb, vld, R2[s]); break;
      case 1: knn_kernel<16><<<dim3(M, 4), 64, 0, stream>>>(P[s], P[s+1], N, M, nb, vld, R2[s]); break;
      case 2: knn_kernel<4><<<dim3(M, 4), 64, 0, stream>>>(P[s], P[s+1], N, M, nb, vld, R2[s]); break;
      default: knn_kernel<1><<<dim3(M, 4), 64, 0, stream>>>(P[s], P[s+1], N, M, nb, vld, R2[s]); break;
    }
    // v = x@lw + lb
    {
      GemmP g{}; g.A = X[s]; g.sA = SXs[s]; g.W = lin_w + (long)s*147456; g.bias = lin_b + (long)s*384;
      g.C = vb; g.sC = SV; g.R = N;
      gemm_kernel<0, false, true, false><<<dim3(N/64, 6, 4), 256, 0, stream>>>(g);
    }
    // a_src = x@sw
    {
      GemmP g{}; g.A = X[s]; g.sA = SXs[s]; g.W = src_w + (long)s*147456;
      g.C = asb; g.sC = SV; g.R = N;
      gemm_kernel<0, false, false, false><<<dim3(N/64, 6, 4), 256, 0, stream>>>(g);
    }
    // a_dst = x[idx]@dw
    {
      GemmP g{}; g.A = X[s]; g.sA = SXs[s]; g.W = dst_w + (long)s*147456;
      g.C = adb; g.sC = SAD; g.R = M; g.gather = ix[s]; g.sG = M;
      gemm_kernel<0, true, false, false><<<dim3((M+63)/64, 6, 4), 256, 0, stream>>>(g);
    }
    // chunks of 256 queries: delta GEMM, alpha GEMM, softmax+LN
    const int nch = (M + 255) / 256;
    for (int c = 0; c < nch; c++) {
      const int q0 = c * 256;
      const int Mc = (M - q0 < 256) ? (M - q0) : 256;
      const int rows = Mc * 16;
      {
        GemmP g{}; g.W = pos_w2 + (long)s*147456; g.bias = pos_b2 + (long)s*384;
        g.C = db; g.sC = SCH; g.R = rows;
        g.qpos = P[s+1]; g.sQ = SPs[s+1]; g.pos = P[s]; g.sP = SPs[s];
        g.nbr = nb; g.sN = SNB; g.pw1 = pos_w1 + (long)s*1152; g.pb1 = pos_b1 + (long)s*384;
        g.row0 = q0 * 16;
        gemm_kernel<1, false, true, true><<<dim3(rows/64, 6, 4), 256, 0, stream>>>(g);
      }
      {
        GemmP g{}; g.A = db; g.sA = SCH; g.W = attn_w + (long)s*147456; g.bias = attn_b + (long)s*384;
        g.C = ab; g.sC = SCH; g.R = rows;
        g.nbr = nb; g.sN = SNB; g.adst = adb; g.sAD = SAD; g.asrc = asb; g.sAS = SV;
        g.row0 = q0 * 16;
        gemm_kernel<2, false, true, true><<<dim3(rows/64, 6, 4), 256, 0, stream>>>(g);
      }
      attnln_kernel<<<dim3(Mc, 4), 128, 0, stream>>>(
          ab, db, vb, nb, vld, ln_g + (long)s*384, ln_b + (long)s*384,
          X[s+1], q0, SCH, SV, SNB, (long)M*384);
    }
  }

  feat_kernel<<<dim3(16, 4), 384, 0, stream>>>(x4, proj_w, proj_b, pln_g, pln_b, out + 192);
  tail_kernel<<<1, 256, 0, stream>>>(p4, out);
}

// Round 3
// 2796.505 us; speedup vs baseline: 1.7318x; 1.7318x over previous
//
#include <hip/hip_runtime.h>
#include <math.h>

// ---------------------------------------------------------------------------
// GlobalSceneEncoder: 4-stage point-transformer encoder.
// f64 selections (FPS/KNN), f16 MFMA GEMMs w/ fp32 accum, fp32 elsewhere.
// B=4, N0=4096, D=384, K=16.
// ---------------------------------------------------------------------------

using half8 = __attribute__((ext_vector_type(8))) _Float16;
using f32x4 = __attribute__((ext_vector_type(4))) float;

// ---------------- split pts -> pos0, x0 ----------------
__global__ __launch_bounds__(128) void split_kernel(
    const float* __restrict__ pts, float* __restrict__ pos0, float* __restrict__ x0)
{
  const int n = blockIdx.x;
  const int b = blockIdx.y;
  const float* src = pts + ((long)b * 4096 + n) * 387;
  float* pd = pos0 + ((long)b * 4096 + n) * 3;
  float* xd = x0 + ((long)b * 4096 + n) * 384;
  for (int e = threadIdx.x; e < 387; e += 128) {
    float v = src[e];
    if (e < 3) pd[e] = v; else xd[e - 3] = v;
  }
}

// ---------------- weight transpose + f16 convert: Wt[n][k] = W[k][n] -------
struct TP { const float* src[5]; _Float16* dst; };
__global__ __launch_bounds__(256) void transpose_kernel(TP p)
{
  const int z = blockIdx.z;
  const float* S = p.src[z >> 2] + (long)(z & 3) * 147456;
  _Float16* Dst = p.dst + (long)z * 147456;
  const int k0 = blockIdx.x * 32, n0 = blockIdx.y * 32;
  __shared__ float tile[32][33];
  const int ti = threadIdx.x & 31, tj = threadIdx.x >> 5;  // 8 rows/pass
  #pragma unroll
  for (int p8 = 0; p8 < 32; p8 += 8)
    tile[tj + p8][ti] = S[(long)(k0 + tj + p8) * 384 + n0 + ti];
  __syncthreads();
  #pragma unroll
  for (int p8 = 0; p8 < 32; p8 += 8)
    Dst[(long)(n0 + tj + p8) * 384 + k0 + ti] = (_Float16)tile[ti][tj + p8];
}

// ---------------- FPS: one block per batch, sequential M-1 steps -----------
// R1 topology (2 barriers, wave-0 second reduce) + LDS position cache.
template<int NPTS, int NTHR>
__global__ __launch_bounds__(NTHR) void fps_kernel(
    const float* __restrict__ pos,
    int* __restrict__ idx_out, float* __restrict__ pos_out)
{
  constexpr int NPT = NPTS / NTHR;
  constexpr int NW = NTHR / 64;
  constexpr int M = NPTS / 4;
  const int b = blockIdx.x;
  pos += (long)b * NPTS * 3; idx_out += (long)b * M; pos_out += (long)b * M * 3;
  const int t = threadIdx.x;

  __shared__ float spx[NPTS], spy[NPTS], spz[NPTS];
  __shared__ double s_val[NW > 1 ? NW : 1];
  __shared__ int s_idx[NW > 1 ? NW : 1];
  __shared__ int s_sel;

  float px[NPT], py[NPT], pz[NPT];
  double dmin[NPT];
  #pragma unroll
  for (int i = 0; i < NPT; i++) {
    const int j = i * NTHR + t;
    px[i] = pos[j*3]; py[i] = pos[j*3+1]; pz[i] = pos[j*3+2];
    spx[j] = px[i]; spy[j] = py[i]; spz[j] = pz[i];
  }
  const float sxf = pos[0], syf = pos[1], szf = pos[2];
  {
    const double sx = sxf, sy = syf, sz = szf;
    #pragma unroll
    for (int i = 0; i < NPT; i++) {
      double dx = (double)px[i]-sx, dy = (double)py[i]-sy, dz = (double)pz[i]-sz;
      dmin[i] = dx*dx + dy*dy + dz*dz;
    }
  }
  if (t == 0) { idx_out[0] = 0; pos_out[0] = sxf; pos_out[1] = syf; pos_out[2] = szf; }
  if (NW > 1) __syncthreads();   // spx/spy/spz visible

  for (int m = 1; m < M; ++m) {
    double best = -1.0; int bj = 0x7fffffff;
    #pragma unroll
    for (int i = 0; i < NPT; i++)
      if (dmin[i] > best) { best = dmin[i]; bj = i * NTHR + t; }
    #pragma unroll
    for (int off = 32; off; off >>= 1) {
      double ov = __shfl_xor(best, off); int oj = __shfl_xor(bj, off);
      if (ov > best || (ov == best && oj < bj)) { best = ov; bj = oj; }
    }
    int sel;
    if (NW > 1) {
      if ((t & 63) == 0) { s_val[t >> 6] = best; s_idx[t >> 6] = bj; }
      __syncthreads();
      if (t < 64) {
        double v = (t < NW) ? s_val[t] : -1.0;
        int j = (t < NW) ? s_idx[t] : 0x7fffffff;
        #pragma unroll
        for (int off = NW >> 1; off; off >>= 1) {
          double ov = __shfl_xor(v, off); int oj = __shfl_xor(j, off);
          if (ov > v || (ov == v && oj < j)) { v = ov; j = oj; }
        }
        if (t == 0) s_sel = j;
      }
      __syncthreads();
      sel = s_sel;
    } else {
      sel = bj;
    }
    const float qxf = spx[sel], qyf = spy[sel], qzf = spz[sel];
    const double qx = qxf, qy = qyf, qz = qzf;
    #pragma unroll
    for (int i = 0; i < NPT; i++) {
      double dx = (double)px[i]-qx, dy = (double)py[i]-qy, dz = (double)pz[i]-qz;
      double dd = dx*dx + dy*dy + dz*dz;
      if (dd < dmin[i]) dmin[i] = dd;
    }
    if (t == 0) { idx_out[m] = sel; pos_out[m*3] = qxf; pos_out[m*3+1] = qyf; pos_out[m*3+2] = qzf; }
  }
}

// ---------------- KNN: one wave per query, 16 lexicographic-min passes -----
template<int C>
__global__ __launch_bounds__(64) void knn_kernel(
    const float* __restrict__ pos, const float* __restrict__ qpos,
    int N, int M, int* __restrict__ nbr, float* __restrict__ vld, double r2)
{
  const int m = blockIdx.x, b = blockIdx.y;
  pos += (long)b * N * 3; qpos += (long)b * M * 3;
  nbr += (long)b * (1024 * 16); vld += (long)b * (1024 * 16);
  const int lane = threadIdx.x;
  const double qx = qpos[m*3], qy = qpos[m*3+1], qz = qpos[m*3+2];
  double d[C];
  #pragma unroll
  for (int c = 0; c < C; c++) {
    const int j = c * 64 + lane;
    double dx = (double)pos[j*3] - qx;
    double dy = (double)pos[j*3+1] - qy;
    double dz = (double)pos[j*3+2] - qz;
    d[c] = dx*dx + dy*dy + dz*dz;
  }
  double pd = -1.0; int pj = -1;
  for (int k = 0; k < 16; k++) {
    double best = 1e300; int bj = 0x7fffffff;
    #pragma unroll
    for (int c = 0; c < C; c++) {
      const int j = c * 64 + lane;
      const bool after = (d[c] > pd) || (d[c] == pd && j > pj);
      if (after && d[c] < best) { best = d[c]; bj = j; }
    }
    #pragma unroll
    for (int off = 32; off; off >>= 1) {
      double ov = __shfl_xor(best, off); int oj = __shfl_xor(bj, off);
      if (ov < best || (ov == best && oj < bj)) { best = ov; bj = oj; }
    }
    pd = best; pj = bj;
    if (lane == 0) { nbr[m*16+k] = bj; vld[m*16+k] = (best <= r2) ? 1.0f : 0.0f; }
  }
}

// ---------------- f16 MFMA GEMM, 64x64 tile, BK=32, 3 A-operand modes ------
// AMODE 0: A = rows of p.A (optional gather)     -> v / a_src / a_dst
// AMODE 1: A = relu(rel @ pw1 + pb1) on the fly  -> delta GEMM
// AMODE 2: A = a_dst[m] - a_src[nbr] + delta     -> alpha GEMM
struct GemmP {
  const float* A; long sA;
  const _Float16* Wt;          // pre-transposed f16 weights: Wt[n][k]
  const float* bias;
  float* C; long sC;
  int R;
  const int* gather; long sG;
  const float* qpos; long sQ;
  const float* pos;  long sP;
  const int* nbr;    long sN;
  const float* pw1;
  const float* pb1;
  const float* adst; long sAD;
  const float* asrc; long sAS;
  int row0;
};

template<int AMODE, bool GATHER, bool BIAS, bool RELU>
__global__ __launch_bounds__(256) void mgemm_kernel(GemmP p)
{
  const int b = blockIdx.z;
  const int rb = blockIdx.x * 64;
  const int cb = blockIdx.y * 64;
  const int t = threadIdx.x;
  const float* A = p.A ? (p.A + (long)b * p.sA) : nullptr;
  float* C = p.C + (long)b * p.sC;
  const int* gat = GATHER ? (p.gather + (long)b * p.sG) : nullptr;
  const int* nbrb = (AMODE != 0) ? (p.nbr + (long)b * p.sN) : nullptr;

  __shared__ _Float16 As[64][40];   // pad 40 halves = 80B -> only free 2-way conflicts
  __shared__ _Float16 Bs[64][40];

  const int w = t >> 6, lane = t & 63;
  const int wm = w & 1, wn = w >> 1;
  const int quad = lane >> 4, l16 = lane & 15;

  f32x4 acc[2][2] = {};

  // ---- staging row-invariants (thread t owns A-tile row sr, k-off sk) ----
  const int sr = t >> 2;
  const int sk = (t & 3) << 3;
  const int ar = rb + sr;

  const float* arow = nullptr;
  const float* adrow = nullptr;
  const float* asrow = nullptr;
  bool avalid = true;
  float rx = 0.f, ry = 0.f, rz = 0.f;
  if (AMODE == 0) {
    avalid = (ar < p.R);
    long srcrow = 0;
    if (avalid) srcrow = GATHER ? (long)gat[ar] : (long)ar;
    arow = A + srcrow * 384;
  } else {
    const int grow = p.row0 + ar;
    const int mq = grow >> 4;
    const int n = nbrb[grow];
    if (AMODE == 1) {
      const float* qposb = p.qpos + (long)b * p.sQ;
      const float* posb = p.pos + (long)b * p.sP;
      rx = qposb[mq*3+0] - posb[n*3+0];
      ry = qposb[mq*3+1] - posb[n*3+1];
      rz = qposb[mq*3+2] - posb[n*3+2];
    } else {
      arow = A + (long)ar * 384;                       // delta row
      adrow = p.adst + (long)b * p.sAD + (long)mq * 384;
      asrow = p.asrc + (long)b * p.sAS + (long)n * 384;
    }
  }

  for (int k0 = 0; k0 < 384; k0 += 32) {
    // ---- produce 8 fp32 A values for (sr, k0+sk..+7) ----
    float a8[8];
    if (AMODE == 0) {
      if (avalid) {
        const float4 u = *(const float4*)(arow + k0 + sk);
        const float4 v = *(const float4*)(arow + k0 + sk + 4);
        a8[0]=u.x; a8[1]=u.y; a8[2]=u.z; a8[3]=u.w;
        a8[4]=v.x; a8[5]=v.y; a8[6]=v.z; a8[7]=v.w;
      } else {
        #pragma unroll
        for (int j = 0; j < 8; j++) a8[j] = 0.f;
      }
    } else if (AMODE == 1) {
      const int kc = k0 + sk;
      const float4 w0a = *(const float4*)(p.pw1 + kc);
      const float4 w0b = *(const float4*)(p.pw1 + kc + 4);
      const float4 w1a = *(const float4*)(p.pw1 + 384 + kc);
      const float4 w1b = *(const float4*)(p.pw1 + 384 + kc + 4);
      const float4 w2a = *(const float4*)(p.pw1 + 768 + kc);
      const float4 w2b = *(const float4*)(p.pw1 + 768 + kc + 4);
      const float4 b1a = *(const float4*)(p.pb1 + kc);
      const float4 b1b = *(const float4*)(p.pb1 + kc + 4);
      a8[0] = fmaxf(rx*w0a.x + ry*w1a.x + rz*w2a.x + b1a.x, 0.f);
      a8[1] = fmaxf(rx*w0a.y + ry*w1a.y + rz*w2a.y + b1a.y, 0.f);
      a8[2] = fmaxf(rx*w0a.z + ry*w1a.z + rz*w2a.z + b1a.z, 0.f);
      a8[3] = fmaxf(rx*w0a.w + ry*w1a.w + rz*w2a.w + b1a.w, 0.f);
      a8[4] = fmaxf(rx*w0b.x + ry*w1b.x + rz*w2b.x + b1b.x, 0.f);
      a8[5] = fmaxf(rx*w0b.y + ry*w1b.y + rz*w2b.y + b1b.y, 0.f);
      a8[6] = fmaxf(rx*w0b.z + ry*w1b.z + rz*w2b.z + b1b.z, 0.f);
      a8[7] = fmaxf(rx*w0b.w + ry*w1b.w + rz*w2b.w + b1b.w, 0.f);
    } else {
      const int kc = k0 + sk;
      const float4 d0 = *(const float4*)(arow + kc);
      const float4 d1 = *(const float4*)(arow + kc + 4);
      const float4 a0 = *(const float4*)(adrow + kc);
      const float4 a1 = *(const float4*)(adrow + kc + 4);
      const float4 s0 = *(const float4*)(asrow + kc);
      const float4 s1 = *(const float4*)(asrow + kc + 4);
      a8[0] = a0.x - s0.x + d0.x; a8[1] = a0.y - s0.y + d0.y;
      a8[2] = a0.z - s0.z + d0.z; a8[3] = a0.w - s0.w + d0.w;
      a8[4] = a1.x - s1.x + d1.x; a8[5] = a1.y - s1.y + d1.y;
      a8[6] = a1.z - s1.z + d1.z; a8[7] = a1.w - s1.w + d1.w;
    }
    // B tile rows: Wt[cb+sr][k0+sk..+7], already f16
    const half8 bv = *(const half8*)(p.Wt + (long)(cb + sr) * 384 + k0 + sk);

    __syncthreads();   // previous iteration's frag reads complete
    half8 av;
    #pragma unroll
    for (int j = 0; j < 8; j++) av[j] = (_Float16)a8[j];
    *(half8*)&As[sr][sk] = av;
    *(half8*)&Bs[sr][sk] = bv;
    __syncthreads();

    const half8 fa0 = *(const half8*)&As[wm*32 + l16][quad*8];
    const half8 fa1 = *(const half8*)&As[wm*32 + 16 + l16][quad*8];
    const half8 fb0 = *(const half8*)&Bs[wn*32 + l16][quad*8];
    const half8 fb1 = *(const half8*)&Bs[wn*32 + 16 + l16][quad*8];
    acc[0][0] = __builtin_amdgcn_mfma_f32_16x16x32_f16(fa0, fb0, acc[0][0], 0, 0, 0);
    acc[0][1] = __builtin_amdgcn_mfma_f32_16x16x32_f16(fa0, fb1, acc[0][1], 0, 0, 0);
    acc[1][0] = __builtin_amdgcn_mfma_f32_16x16x32_f16(fa1, fb0, acc[1][0], 0, 0, 0);
    acc[1][1] = __builtin_amdgcn_mfma_f32_16x16x32_f16(fa1, fb1, acc[1][1], 0, 0, 0);
  }

  // ---- epilogue: C[row][col], row = base + quad*4 + reg, col = cb+wn*32+j*16+l16
  float bi0 = 0.f, bi1 = 0.f;
  if (BIAS) {
    bi0 = p.bias[cb + wn*32 + l16];
    bi1 = p.bias[cb + wn*32 + 16 + l16];
  }
  #pragma unroll
  for (int i = 0; i < 2; i++) {
    const int base = rb + wm*32 + i*16;
    if (base < p.R) {
      const int r0 = base + quad*4;
      #pragma unroll
      for (int j = 0; j < 2; j++) {
        const int col = cb + wn*32 + j*16 + l16;
        const float bb = j ? bi1 : bi0;
        #pragma unroll
        for (int reg = 0; reg < 4; reg++) {
          float v = acc[i][j][reg] + bb;
          if (RELU) v = fmaxf(v, 0.f);
          C[(long)(r0 + reg) * 384 + col] = v;
        }
      }
    }
  }
}

// ---------------- masked softmax over K + weighted sum + LayerNorm ---------
__global__ __launch_bounds__(128) void attnln_kernel(
    const float* __restrict__ alpha, const float* __restrict__ delta,
    const float* __restrict__ vbuf, const int* __restrict__ nbr,
    const float* __restrict__ vldb, const float* __restrict__ lng,
    const float* __restrict__ lnb, float* __restrict__ xout,
    int q0, long sCh, long sV, long sNb, long sX)
{
  const int ml = blockIdx.x, b = blockIdx.y;
  const int m = q0 + ml;
  alpha += (long)b * sCh; delta += (long)b * sCh; vbuf += (long)b * sV;
  nbr += (long)b * sNb; vldb += (long)b * sNb; xout += (long)b * sX;
  const int t = threadIdx.x;

  int nb[16]; float vl[16];
  #pragma unroll
  for (int k = 0; k < 16; k++) { nb[k] = nbr[m*16+k]; vl[k] = vldb[m*16+k]; }

  const long rbase = (long)ml * 16 * 384;
  float av[16][3];
  #pragma unroll
  for (int k = 0; k < 16; k++)
    #pragma unroll
    for (int i = 0; i < 3; i++) {
      const float a = alpha[rbase + k*384 + t + i*128];
      av[k][i] = (vl[k] > 0.5f) ? a : -1e30f;
    }
  float mx[3] = {-3.4e38f, -3.4e38f, -3.4e38f};
  #pragma unroll
  for (int k = 0; k < 16; k++)
    #pragma unroll
    for (int i = 0; i < 3; i++) mx[i] = fmaxf(mx[i], av[k][i]);
  float sm[3] = {0.f, 0.f, 0.f};
  #pragma unroll
  for (int k = 0; k < 16; k++)
    #pragma unroll
    for (int i = 0; i < 3; i++) { const float e = expf(av[k][i] - mx[i]); av[k][i] = e; sm[i] += e; }
  float rs[3];
  #pragma unroll
  for (int i = 0; i < 3; i++) rs[i] = 1.0f / sm[i];
  float o[3] = {0.f, 0.f, 0.f};
  #pragma unroll
  for (int k = 0; k < 16; k++) {
    const long nrow = (long)nb[k] * 384;
    #pragma unroll
    for (int i = 0; i < 3; i++) {
      const int dd = t + i * 128;
      const float vv = vbuf[nrow + dd] + delta[rbase + k*384 + dd];
      o[i] += (av[k][i] * rs[i] * vl[k]) * vv;
    }
  }
  __shared__ float sred[2];
  float s1 = o[0] + o[1] + o[2];
  #pragma unroll
  for (int off = 32; off; off >>= 1) s1 += __shfl_xor(s1, off);
  if ((t & 63) == 0) sred[t >> 6] = s1;
  __syncthreads();
  const float mean = (sred[0] + sred[1]) * (1.0f / 384.0f);
  __syncthreads();
  float s2 = 0.f;
  #pragma unroll
  for (int i = 0; i < 3; i++) { const float dd = o[i] - mean; s2 += dd * dd; }
  #pragma unroll
  for (int off = 32; off; off >>= 1) s2 += __shfl_xor(s2, off);
  if ((t & 63) == 0) sred[t >> 6] = s2;
  __syncthreads();
  const float var = (sred[0] + sred[1]) * (1.0f / 384.0f);
  const float rstd = 1.0f / sqrtf(var + 1e-5f);
  #pragma unroll
  for (int i = 0; i < 3; i++) {
    const int dd = t + i * 128;
    xout[(long)m * 384 + dd] = (o[i] - mean) * rstd * lng[dd] + lnb[dd];
  }
}

// ---------------- final projection + LayerNorm -----------------------------
__global__ __launch_bounds__(384) void feat_kernel(
    const float* __restrict__ x4, const float* __restrict__ pw,
    const float* __restrict__ pb, const float* __restrict__ g,
    const float* __restrict__ be, float* __restrict__ outf)
{
  const int row = blockIdx.x, b = blockIdx.y;
  const long r = (long)b * 16 + row;
  const int d = threadIdx.x;
  __shared__ float xs[384];
  xs[d] = x4[r * 384 + d];
  __syncthreads();
  float acc = pb[d];
  #pragma unroll 8
  for (int j = 0; j < 384; j++) acc = fmaf(xs[j], pw[(long)j * 384 + d], acc);
  __shared__ float sred[6];
  float s = acc;
  #pragma unroll
  for (int off = 32; off; off >>= 1) s += __shfl_xor(s, off);
  if ((d & 63) == 0) sred[d >> 6] = s;
  __syncthreads();
  const float mean = (sred[0]+sred[1]+sred[2]+sred[3]+sred[4]+sred[5]) * (1.0f/384.0f);
  __syncthreads();
  float dv = (acc - mean) * (acc - mean);
  #pragma unroll
  for (int off = 32; off; off >>= 1) dv += __shfl_xor(dv, off);
  if ((d & 63) == 0) sred[d >> 6] = dv;
  __syncthreads();
  const float var = (sred[0]+sred[1]+sred[2]+sred[3]+sred[4]+sred[5]) * (1.0f/384.0f);
  const float rstd = 1.0f / sqrtf(var + 1e-5f);
  outf[r * 384 + d] = (acc - mean) * rstd * g[d] + be[d];
}

// ---------------- pos + pad outputs ----------------------------------------
__global__ void tail_kernel(const float* __restrict__ p4, float* __restrict__ out)
{
  const int t = threadIdx.x;
  if (t < 192) out[t] = p4[t];
  if (t < 64) out[192 + 24576 + t] = 0.0f;
}

// ---------------------------------------------------------------------------
extern "C" void kernel_launch(void* const* d_in, const int* in_sizes, int n_in,
                              void* d_out, int out_size, void* d_ws, size_t ws_size,
                              hipStream_t stream)
{
  (void)in_sizes; (void)n_in; (void)out_size; (void)ws_size;
  const float* pts    = (const float*)d_in[0];
  const float* lin_w  = (const float*)d_in[1];
  const float* lin_b  = (const float*)d_in[2];
  const float* src_w  = (const float*)d_in[3];
  const float* dst_w  = (const float*)d_in[4];
  const float* pos_w1 = (const float*)d_in[5];
  const float* pos_b1 = (const float*)d_in[6];
  const float* pos_w2 = (const float*)d_in[7];
  const float* pos_b2 = (const float*)d_in[8];
  const float* attn_w = (const float*)d_in[9];
  const float* attn_b = (const float*)d_in[10];
  const float* ln_g   = (const float*)d_in[11];
  const float* ln_b   = (const float*)d_in[12];
  const float* proj_w = (const float*)d_in[13];
  const float* proj_b = (const float*)d_in[14];
  const float* pln_g  = (const float*)d_in[15];
  const float* pln_b  = (const float*)d_in[16];
  float* out = (float*)d_out;

  // ---- workspace layout ----
  constexpr long SX0 = 4096L*384, SX1 = 1024L*384, SX2 = 256L*384, SX3 = 64L*384, SX4 = 16L*384;
  constexpr long SP0 = 4096L*3, SP1 = 1024L*3, SP2 = 256L*3, SP3 = 64L*3, SP4 = 16L*3;
  constexpr long SV  = 4096L*384;
  constexpr long SAD = 1024L*384;
  constexpr long SCH = 4096L*384;
  constexpr long SNB = 1024L*16;

  _Float16* wt = (_Float16*)d_ws;              // 20 matrices, 5.9 MB, 16B aligned
  float* ws = (float*)(wt + 20L * 147456);
  float* x0 = ws; ws += 4*SX0;
  float* x1 = ws; ws += 4*SX1;
  float* x2 = ws; ws += 4*SX2;
  float* x3 = ws; ws += 4*SX3;
  float* x4 = ws; ws += 4*SX4;
  float* p0 = ws; ws += 4*SP0;
  float* p1 = ws; ws += 4*SP1;
  float* p2 = ws; ws += 4*SP2;
  float* p3 = ws; ws += 4*SP3;
  float* p4 = ws; ws += 4*SP4;
  float* vb = ws; ws += 4*SV;
  float* asb = ws; ws += 4*SV;
  float* adb = ws; ws += 4*SAD;
  float* db = ws; ws += 4*SCH;
  float* ab = ws; ws += 4*SCH;
  float* vld = ws; ws += 4*SNB;
  int* nb = (int*)ws; ws += 4*SNB;
  int* ix[4];
  ix[0] = (int*)ws; ws += 4*1024;
  ix[1] = (int*)ws; ws += 4*256;
  ix[2] = (int*)ws; ws += 4*64;
  ix[3] = (int*)ws; ws += 4*16;

  const int Ns[4] = {4096, 1024, 256, 64};
  const int Ms[4] = {1024, 256, 64, 16};
  const double R2[4] = {1.0, 4.0, 16.0, 64.0};
  float* X[5] = {x0, x1, x2, x3, x4};
  float* P[5] = {p0, p1, p2, p3, p4};
  long SPs[5] = {SP0, SP1, SP2, SP3, SP4};
  long SXs[5] = {SX0, SX1, SX2, SX3, SX4};

  // split pts
  split_kernel<<<dim3(4096, 4), 128, 0, stream>>>(pts, p0, x0);

  // weight transpose + f16 (ids: lin=0..3, src=4..7, dst=8..11, posw2=12..15, attn=16..19)
  {
    TP tp{};
    tp.src[0] = lin_w; tp.src[1] = src_w; tp.src[2] = dst_w;
    tp.src[3] = pos_w2; tp.src[4] = attn_w;
    tp.dst = wt;
    transpose_kernel<<<dim3(12, 12, 20), 256, 0, stream>>>(tp);
  }

  // FPS chain
  fps_kernel<4096, 512><<<dim3(4), 512, 0, stream>>>(P[0], ix[0], P[1]);
  fps_kernel<1024, 256><<<dim3(4), 256, 0, stream>>>(P[1], ix[1], P[2]);
  fps_kernel<256, 256><<<dim3(4), 256, 0, stream>>>(P[2], ix[2], P[3]);
  fps_kernel<64, 64><<<dim3(4), 64, 0, stream>>>(P[3], ix[3], P[4]);

  for (int s = 0; s < 4; s++) {
    const int N = Ns[s], M = Ms[s];
    switch (s) {
      case 0: knn_kernel<64><<<dim3(M, 4), 64, 0, stream>>>(P[s], P[s+1], N, M, nb, vld, R2[s]); break;
      case 1: knn_kernel<16><<<dim3(M, 4), 64, 0, stream>>>(P[s], P[s+1], N, M, nb, vld, R2[s]); break;
      case 2: knn_kernel<4><<<dim3(M, 4), 64, 0, stream>>>(P[s], P[s+1], N, M, nb, vld, R2[s]); break;
      default: knn_kernel<1><<<dim3(M, 4), 64, 0, stream>>>(P[s], P[s+1], N, M, nb, vld, R2[s]); break;
    }
    // v = x@lw + lb
    {
      GemmP g{}; g.A = X[s]; g.sA = SXs[s]; g.Wt = wt + (long)(0*4+s)*147456; g.bias = lin_b + (long)s*384;
      g.C = vb; g.sC = SV; g.R = N;
      mgemm_kernel<0, false, true, false><<<dim3(N/64, 6, 4), 256, 0, stream>>>(g);
    }
    // a_src = x@sw
    {
      GemmP g{}; g.A = X[s]; g.sA = SXs[s]; g.Wt = wt + (long)(1*4+s)*147456;
      g.C = asb; g.sC = SV; g.R = N;
      mgemm_kernel<0, false, false, false><<<dim3(N/64, 6, 4), 256, 0, stream>>>(g);
    }
    // a_dst = x[idx]@dw
    {
      GemmP g{}; g.A = X[s]; g.sA = SXs[s]; g.Wt = wt + (long)(2*4+s)*147456;
      g.C = adb; g.sC = SAD; g.R = M; g.gather = ix[s]; g.sG = M;
      mgemm_kernel<0, true, false, false><<<dim3((M+63)/64, 6, 4), 256, 0, stream>>>(g);
    }
    // chunks of 256 queries: delta GEMM, alpha GEMM, softmax+LN
    const int nch = (M + 255) / 256;
    for (int c = 0; c < nch; c++) {
      const int q0 = c * 256;
      const int Mc = (M - q0 < 256) ? (M - q0) : 256;
      const int rows = Mc * 16;
      {
        GemmP g{}; g.Wt = wt + (long)(3*4+s)*147456; g.bias = pos_b2 + (long)s*384;
        g.C = db; g.sC = SCH; g.R = rows;
        g.qpos = P[s+1]; g.sQ = SPs[s+1]; g.pos = P[s]; g.sP = SPs[s];
        g.nbr = nb; g.sN = SNB; g.pw1 = pos_w1 + (long)s*1152; g.pb1 = pos_b1 + (long)s*384;
        g.row0 = q0 * 16;
        mgemm_kernel<1, false, true, true><<<dim3(rows/64, 6, 4), 256, 0, stream>>>(g);
      }
      {
        GemmP g{}; g.A = db; g.sA = SCH; g.Wt = wt + (long)(4*4+s)*147456; g.bias = attn_b + (long)s*384;
        g.C = ab; g.sC = SCH; g.R = rows;
        g.nbr = nb; g.sN = SNB; g.adst = adb; g.sAD = SAD; g.asrc = asb; g.sAS = SV;
        g.row0 = q0 * 16;
        mgemm_kernel<2, false, true, true><<<dim3(rows/64, 6, 4), 256, 0, stream>>>(g);
      }
      attnln_kernel<<<dim3(Mc, 4), 128, 0, stream>>>(
          ab, db, vb, nb, vld, ln_g + (long)s*384, ln_b + (long)s*384,
          X[s+1], q0, SCH, SV, SNB, (long)M*384);
    }
  }

  feat_kernel<<<dim3(16, 4), 384, 0, stream>>>(x4, proj_w, proj_b, pln_g, pln_b, out + 192);
  tail_kernel<<<1, 256, 0, stream>>>(p4, out);
}

// Round 4
// 2502.630 us; speedup vs baseline: 1.9351x; 1.1174x over previous
//
#include <hip/hip_runtime.h>
#include <math.h>

// ---------------------------------------------------------------------------
// GlobalSceneEncoder: 4-stage point-transformer encoder.
// f64 selections (FPS/KNN), f16 MFMA GEMMs w/ fp32 accum, fp32 elsewhere.
// B=4, N0=4096, D=384, K=16.
// ---------------------------------------------------------------------------

using half8 = __attribute__((ext_vector_type(8))) _Float16;
using f32x4 = __attribute__((ext_vector_type(4))) float;

// ---------------- split pts -> pos0, x0 ----------------
__global__ __launch_bounds__(128) void split_kernel(
    const float* __restrict__ pts, float* __restrict__ pos0, float* __restrict__ x0)
{
  const int n = blockIdx.x;
  const int b = blockIdx.y;
  const float* src = pts + ((long)b * 4096 + n) * 387;
  float* pd = pos0 + ((long)b * 4096 + n) * 3;
  float* xd = x0 + ((long)b * 4096 + n) * 384;
  for (int e = threadIdx.x; e < 387; e += 128) {
    float v = src[e];
    if (e < 3) pd[e] = v; else xd[e - 3] = v;
  }
}

// ---------------- weight transpose + f16 convert: Wt[n][k] = W[k][n] -------
struct TP { const float* src[5]; _Float16* dst; };
__global__ __launch_bounds__(256) void transpose_kernel(TP p)
{
  const int z = blockIdx.z;
  const float* S = p.src[z >> 2] + (long)(z & 3) * 147456;
  _Float16* Dst = p.dst + (long)z * 147456;
  const int k0 = blockIdx.x * 32, n0 = blockIdx.y * 32;
  __shared__ float tile[32][33];
  const int ti = threadIdx.x & 31, tj = threadIdx.x >> 5;  // 8 rows/pass
  #pragma unroll
  for (int p8 = 0; p8 < 32; p8 += 8)
    tile[tj + p8][ti] = S[(long)(k0 + tj + p8) * 384 + n0 + ti];
  __syncthreads();
  #pragma unroll
  for (int p8 = 0; p8 < 32; p8 += 8)
    Dst[(long)(n0 + tj + p8) * 384 + k0 + ti] = (_Float16)tile[ti][tj + p8];
}

// ---------------- FPS v3: one barrier/step, tree argmax, f64 reg positions -
template<int NPTS, int NTHR>
__global__ __launch_bounds__(NTHR, 1) void fps_kernel(
    const float* __restrict__ pos,
    int* __restrict__ idx_out, float* __restrict__ pos_out)
{
  constexpr int NPT = NPTS / NTHR;
  constexpr int NW = NTHR / 64;
  constexpr int M = NPTS / 4;
  const int b = blockIdx.x;
  pos += (long)b * NPTS * 3; idx_out += (long)b * M; pos_out += (long)b * M * 3;
  const int t = threadIdx.x;

  __shared__ float spx[NPTS], spy[NPTS], spz[NPTS];
  __shared__ double s_val[2][NW > 1 ? NW : 1];
  __shared__ int s_idx[2][NW > 1 ? NW : 1];

  double px[NPT], py[NPT], pz[NPT];
  double dmin[NPT];
  #pragma unroll
  for (int i = 0; i < NPT; i++) {
    const int j = i * NTHR + t;
    const float fx = pos[j*3], fy = pos[j*3+1], fz = pos[j*3+2];
    px[i] = fx; py[i] = fy; pz[i] = fz;
    spx[j] = fx; spy[j] = fy; spz[j] = fz;
  }
  const float sxf = pos[0], syf = pos[1], szf = pos[2];
  {
    const double sx = sxf, sy = syf, sz = szf;
    #pragma unroll
    for (int i = 0; i < NPT; i++) {
      double dx = px[i]-sx, dy = py[i]-sy, dz = pz[i]-sz;
      dmin[i] = dx*dx + dy*dy + dz*dz;
    }
  }
  if (t == 0) { idx_out[0] = 0; pos_out[0] = sxf; pos_out[1] = syf; pos_out[2] = szf; }
  if (NW > 1) __syncthreads();   // spx/spy/spz visible

  for (int m = 1; m < M; ++m) {
    // ---- local argmax, log-depth tree (ties -> lower i -> lower index) ----
    double bv[NPT]; int bi[NPT];
    #pragma unroll
    for (int i = 0; i < NPT; i++) { bv[i] = dmin[i]; bi[i] = i * NTHR + t; }
    #pragma unroll
    for (int st = NPT >> 1; st >= 1; st >>= 1)
      #pragma unroll
      for (int i = 0; i < st; i++)
        if (bv[i + st] > bv[i]) { bv[i] = bv[i + st]; bi[i] = bi[i + st]; }
    double best = bv[0]; int bj = bi[0];
    // ---- wave butterfly (winner in all lanes) ----
    #pragma unroll
    for (int off = 32; off; off >>= 1) {
      double ov = __shfl_xor(best, off); int oj = __shfl_xor(bj, off);
      if (ov > best || (ov == best && oj < bj)) { best = ov; bj = oj; }
    }
    int sel;
    if (NW > 1) {
      const int p = m & 1;
      if ((t & 63) == 0) { s_val[p][t >> 6] = best; s_idx[p][t >> 6] = bj; }
      __syncthreads();
      const int k = t & (NW - 1);
      double v = s_val[p][k]; int j = s_idx[p][k];
      #pragma unroll
      for (int off = NW >> 1; off; off >>= 1) {
        double ov = __shfl_xor(v, off); int oj = __shfl_xor(j, off);
        if (ov > v || (ov == v && oj < j)) { v = ov; j = oj; }
      }
      sel = j;
    } else {
      sel = bj;
    }
    // ---- broadcast position lookup (same-address LDS reads) ----
    const float qxf = spx[sel], qyf = spy[sel], qzf = spz[sel];
    const double qx = qxf, qy = qyf, qz = qzf;
    #pragma unroll
    for (int i = 0; i < NPT; i++) {
      double dx = px[i]-qx, dy = py[i]-qy, dz = pz[i]-qz;
      double dd = dx*dx + dy*dy + dz*dz;
      if (dd < dmin[i]) dmin[i] = dd;
    }
    if (t == 0) { idx_out[m] = sel; pos_out[m*3] = qxf; pos_out[m*3+1] = qyf; pos_out[m*3+2] = qzf; }
  }
}

// ---------------- KNN: one wave per query, 16 lexicographic-min passes -----
template<int C>
__global__ __launch_bounds__(64) void knn_kernel(
    const float* __restrict__ pos, const float* __restrict__ qpos,
    int N, int M, int* __restrict__ nbr, float* __restrict__ vld, double r2)
{
  const int m = blockIdx.x, b = blockIdx.y;
  pos += (long)b * N * 3; qpos += (long)b * M * 3;
  nbr += (long)b * (1024 * 16); vld += (long)b * (1024 * 16);
  const int lane = threadIdx.x;
  const double qx = qpos[m*3], qy = qpos[m*3+1], qz = qpos[m*3+2];
  double d[C];
  #pragma unroll
  for (int c = 0; c < C; c++) {
    const int j = c * 64 + lane;
    double dx = (double)pos[j*3] - qx;
    double dy = (double)pos[j*3+1] - qy;
    double dz = (double)pos[j*3+2] - qz;
    d[c] = dx*dx + dy*dy + dz*dz;
  }
  double pd = -1.0; int pj = -1;
  for (int k = 0; k < 16; k++) {
    double best = 1e300; int bj = 0x7fffffff;
    #pragma unroll
    for (int c = 0; c < C; c++) {
      const int j = c * 64 + lane;
      const bool after = (d[c] > pd) || (d[c] == pd && j > pj);
      if (after && d[c] < best) { best = d[c]; bj = j; }
    }
    #pragma unroll
    for (int off = 32; off; off >>= 1) {
      double ov = __shfl_xor(best, off); int oj = __shfl_xor(bj, off);
      if (ov < best || (ov == best && oj < bj)) { best = ov; bj = oj; }
    }
    pd = best; pj = bj;
    if (lane == 0) { nbr[m*16+k] = bj; vld[m*16+k] = (best <= r2) ? 1.0f : 0.0f; }
  }
}

// ---------------- f16 MFMA GEMM, 64x64 tile, BK=32, 3 A-operand modes ------
// AMODE 0: A = rows of p.A (optional gather)     -> v / a_src / a_dst
// AMODE 1: A = relu(rel @ pw1 + pb1) on the fly  -> delta GEMM
// AMODE 2: A = a_dst[m] - a_src[nbr] + delta     -> alpha GEMM
struct GemmP {
  const float* A; long sA;
  const _Float16* Wt;          // pre-transposed f16 weights: Wt[n][k]
  const float* bias;
  float* C; long sC;
  int R;
  const int* gather; long sG;
  const float* qpos; long sQ;
  const float* pos;  long sP;
  const int* nbr;    long sN;
  const float* pw1;
  const float* pb1;
  const float* adst; long sAD;
  const float* asrc; long sAS;
  int row0;
};

template<int AMODE, bool GATHER, bool BIAS, bool RELU>
__global__ __launch_bounds__(256) void mgemm_kernel(GemmP p)
{
  const int b = blockIdx.z;
  const int rb = blockIdx.x * 64;
  const int cb = blockIdx.y * 64;
  const int t = threadIdx.x;
  const float* A = p.A ? (p.A + (long)b * p.sA) : nullptr;
  float* C = p.C + (long)b * p.sC;
  const int* gat = GATHER ? (p.gather + (long)b * p.sG) : nullptr;
  const int* nbrb = (AMODE != 0) ? (p.nbr + (long)b * p.sN) : nullptr;

  __shared__ _Float16 As[64][40];
  __shared__ _Float16 Bs[64][40];

  const int w = t >> 6, lane = t & 63;
  const int wm = w & 1, wn = w >> 1;
  const int quad = lane >> 4, l16 = lane & 15;

  f32x4 acc[2][2] = {};

  const int sr = t >> 2;
  const int sk = (t & 3) << 3;
  const int ar = rb + sr;

  const float* arow = nullptr;
  const float* adrow = nullptr;
  const float* asrow = nullptr;
  bool avalid = true;
  float rx = 0.f, ry = 0.f, rz = 0.f;
  if (AMODE == 0) {
    avalid = (ar < p.R);
    long srcrow = 0;
    if (avalid) srcrow = GATHER ? (long)gat[ar] : (long)ar;
    arow = A + srcrow * 384;
  } else {
    const int grow = p.row0 + ar;
    const int mq = grow >> 4;
    const int n = nbrb[grow];
    if (AMODE == 1) {
      const float* qposb = p.qpos + (long)b * p.sQ;
      const float* posb = p.pos + (long)b * p.sP;
      rx = qposb[mq*3+0] - posb[n*3+0];
      ry = qposb[mq*3+1] - posb[n*3+1];
      rz = qposb[mq*3+2] - posb[n*3+2];
    } else {
      arow = A + (long)ar * 384;
      adrow = p.adst + (long)b * p.sAD + (long)mq * 384;
      asrow = p.asrc + (long)b * p.sAS + (long)n * 384;
    }
  }

  for (int k0 = 0; k0 < 384; k0 += 32) {
    float a8[8];
    if (AMODE == 0) {
      if (avalid) {
        const float4 u = *(const float4*)(arow + k0 + sk);
        const float4 v = *(const float4*)(arow + k0 + sk + 4);
        a8[0]=u.x; a8[1]=u.y; a8[2]=u.z; a8[3]=u.w;
        a8[4]=v.x; a8[5]=v.y; a8[6]=v.z; a8[7]=v.w;
      } else {
        #pragma unroll
        for (int j = 0; j < 8; j++) a8[j] = 0.f;
      }
    } else if (AMODE == 1) {
      const int kc = k0 + sk;
      const float4 w0a = *(const float4*)(p.pw1 + kc);
      const float4 w0b = *(const float4*)(p.pw1 + kc + 4);
      const float4 w1a = *(const float4*)(p.pw1 + 384 + kc);
      const float4 w1b = *(const float4*)(p.pw1 + 384 + kc + 4);
      const float4 w2a = *(const float4*)(p.pw1 + 768 + kc);
      const float4 w2b = *(const float4*)(p.pw1 + 768 + kc + 4);
      const float4 b1a = *(const float4*)(p.pb1 + kc);
      const float4 b1b = *(const float4*)(p.pb1 + kc + 4);
      a8[0] = fmaxf(rx*w0a.x + ry*w1a.x + rz*w2a.x + b1a.x, 0.f);
      a8[1] = fmaxf(rx*w0a.y + ry*w1a.y + rz*w2a.y + b1a.y, 0.f);
      a8[2] = fmaxf(rx*w0a.z + ry*w1a.z + rz*w2a.z + b1a.z, 0.f);
      a8[3] = fmaxf(rx*w0a.w + ry*w1a.w + rz*w2a.w + b1a.w, 0.f);
      a8[4] = fmaxf(rx*w0b.x + ry*w1b.x + rz*w2b.x + b1b.x, 0.f);
      a8[5] = fmaxf(rx*w0b.y + ry*w1b.y + rz*w2b.y + b1b.y, 0.f);
      a8[6] = fmaxf(rx*w0b.z + ry*w1b.z + rz*w2b.z + b1b.z, 0.f);
      a8[7] = fmaxf(rx*w0b.w + ry*w1b.w + rz*w2b.w + b1b.w, 0.f);
    } else {
      const int kc = k0 + sk;
      const float4 d0 = *(const float4*)(arow + kc);
      const float4 d1 = *(const float4*)(arow + kc + 4);
      const float4 a0 = *(const float4*)(adrow + kc);
      const float4 a1 = *(const float4*)(adrow + kc + 4);
      const float4 s0 = *(const float4*)(asrow + kc);
      const float4 s1 = *(const float4*)(asrow + kc + 4);
      a8[0] = a0.x - s0.x + d0.x; a8[1] = a0.y - s0.y + d0.y;
      a8[2] = a0.z - s0.z + d0.z; a8[3] = a0.w - s0.w + d0.w;
      a8[4] = a1.x - s1.x + d1.x; a8[5] = a1.y - s1.y + d1.y;
      a8[6] = a1.z - s1.z + d1.z; a8[7] = a1.w - s1.w + d1.w;
    }
    const half8 bv = *(const half8*)(p.Wt + (long)(cb + sr) * 384 + k0 + sk);

    __syncthreads();
    half8 av;
    #pragma unroll
    for (int j = 0; j < 8; j++) av[j] = (_Float16)a8[j];
    *(half8*)&As[sr][sk] = av;
    *(half8*)&Bs[sr][sk] = bv;
    __syncthreads();

    const half8 fa0 = *(const half8*)&As[wm*32 + l16][quad*8];
    const half8 fa1 = *(const half8*)&As[wm*32 + 16 + l16][quad*8];
    const half8 fb0 = *(const half8*)&Bs[wn*32 + l16][quad*8];
    const half8 fb1 = *(const half8*)&Bs[wn*32 + 16 + l16][quad*8];
    acc[0][0] = __builtin_amdgcn_mfma_f32_16x16x32_f16(fa0, fb0, acc[0][0], 0, 0, 0);
    acc[0][1] = __builtin_amdgcn_mfma_f32_16x16x32_f16(fa0, fb1, acc[0][1], 0, 0, 0);
    acc[1][0] = __builtin_amdgcn_mfma_f32_16x16x32_f16(fa1, fb0, acc[1][0], 0, 0, 0);
    acc[1][1] = __builtin_amdgcn_mfma_f32_16x16x32_f16(fa1, fb1, acc[1][1], 0, 0, 0);
  }

  float bi0 = 0.f, bi1 = 0.f;
  if (BIAS) {
    bi0 = p.bias[cb + wn*32 + l16];
    bi1 = p.bias[cb + wn*32 + 16 + l16];
  }
  #pragma unroll
  for (int i = 0; i < 2; i++) {
    const int base = rb + wm*32 + i*16;
    if (base < p.R) {
      const int r0 = base + quad*4;
      #pragma unroll
      for (int j = 0; j < 2; j++) {
        const int col = cb + wn*32 + j*16 + l16;
        const float bb = j ? bi1 : bi0;
        #pragma unroll
        for (int reg = 0; reg < 4; reg++) {
          float v = acc[i][j][reg] + bb;
          if (RELU) v = fmaxf(v, 0.f);
          C[(long)(r0 + reg) * 384 + col] = v;
        }
      }
    }
  }
}

// ---------------- masked softmax over K + weighted sum + LayerNorm ---------
__global__ __launch_bounds__(128) void attnln_kernel(
    const float* __restrict__ alpha, const float* __restrict__ delta,
    const float* __restrict__ vbuf, const int* __restrict__ nbr,
    const float* __restrict__ vldb, const float* __restrict__ lng,
    const float* __restrict__ lnb, float* __restrict__ xout,
    int q0, long sCh, long sV, long sNb, long sX)
{
  const int ml = blockIdx.x, b = blockIdx.y;
  const int m = q0 + ml;
  alpha += (long)b * sCh; delta += (long)b * sCh; vbuf += (long)b * sV;
  nbr += (long)b * sNb; vldb += (long)b * sNb; xout += (long)b * sX;
  const int t = threadIdx.x;

  int nb[16]; float vl[16];
  #pragma unroll
  for (int k = 0; k < 16; k++) { nb[k] = nbr[m*16+k]; vl[k] = vldb[m*16+k]; }

  const long rbase = (long)ml * 16 * 384;
  float av[16][3];
  #pragma unroll
  for (int k = 0; k < 16; k++)
    #pragma unroll
    for (int i = 0; i < 3; i++) {
      const float a = alpha[rbase + k*384 + t + i*128];
      av[k][i] = (vl[k] > 0.5f) ? a : -1e30f;
    }
  float mx[3] = {-3.4e38f, -3.4e38f, -3.4e38f};
  #pragma unroll
  for (int k = 0; k < 16; k++)
    #pragma unroll
    for (int i = 0; i < 3; i++) mx[i] = fmaxf(mx[i], av[k][i]);
  float sm[3] = {0.f, 0.f, 0.f};
  #pragma unroll
  for (int k = 0; k < 16; k++)
    #pragma unroll
    for (int i = 0; i < 3; i++) { const float e = expf(av[k][i] - mx[i]); av[k][i] = e; sm[i] += e; }
  float rs[3];
  #pragma unroll
  for (int i = 0; i < 3; i++) rs[i] = 1.0f / sm[i];
  float o[3] = {0.f, 0.f, 0.f};
  #pragma unroll
  for (int k = 0; k < 16; k++) {
    const long nrow = (long)nb[k] * 384;
    #pragma unroll
    for (int i = 0; i < 3; i++) {
      const int dd = t + i * 128;
      const float vv = vbuf[nrow + dd] + delta[rbase + k*384 + dd];
      o[i] += (av[k][i] * rs[i] * vl[k]) * vv;
    }
  }
  __shared__ float sred[2];
  float s1 = o[0] + o[1] + o[2];
  #pragma unroll
  for (int off = 32; off; off >>= 1) s1 += __shfl_xor(s1, off);
  if ((t & 63) == 0) sred[t >> 6] = s1;
  __syncthreads();
  const float mean = (sred[0] + sred[1]) * (1.0f / 384.0f);
  __syncthreads();
  float s2 = 0.f;
  #pragma unroll
  for (int i = 0; i < 3; i++) { const float dd = o[i] - mean; s2 += dd * dd; }
  #pragma unroll
  for (int off = 32; off; off >>= 1) s2 += __shfl_xor(s2, off);
  if ((t & 63) == 0) sred[t >> 6] = s2;
  __syncthreads();
  const float var = (sred[0] + sred[1]) * (1.0f / 384.0f);
  const float rstd = 1.0f / sqrtf(var + 1e-5f);
  #pragma unroll
  for (int i = 0; i < 3; i++) {
    const int dd = t + i * 128;
    xout[(long)m * 384 + dd] = (o[i] - mean) * rstd * lng[dd] + lnb[dd];
  }
}

// ---------------- final projection + LayerNorm -----------------------------
__global__ __launch_bounds__(384) void feat_kernel(
    const float* __restrict__ x4, const float* __restrict__ pw,
    const float* __restrict__ pb, const float* __restrict__ g,
    const float* __restrict__ be, float* __restrict__ outf)
{
  const int row = blockIdx.x, b = blockIdx.y;
  const long r = (long)b * 16 + row;
  const int d = threadIdx.x;
  __shared__ float xs[384];
  xs[d] = x4[r * 384 + d];
  __syncthreads();
  float acc = pb[d];
  #pragma unroll 8
  for (int j = 0; j < 384; j++) acc = fmaf(xs[j], pw[(long)j * 384 + d], acc);
  __shared__ float sred[6];
  float s = acc;
  #pragma unroll
  for (int off = 32; off; off >>= 1) s += __shfl_xor(s, off);
  if ((d & 63) == 0) sred[d >> 6] = s;
  __syncthreads();
  const float mean = (sred[0]+sred[1]+sred[2]+sred[3]+sred[4]+sred[5]) * (1.0f/384.0f);
  __syncthreads();
  float dv = (acc - mean) * (acc - mean);
  #pragma unroll
  for (int off = 32; off; off >>= 1) dv += __shfl_xor(dv, off);
  if ((d & 63) == 0) sred[d >> 6] = dv;
  __syncthreads();
  const float var = (sred[0]+sred[1]+sred[2]+sred[3]+sred[4]+sred[5]) * (1.0f/384.0f);
  const float rstd = 1.0f / sqrtf(var + 1e-5f);
  outf[r * 384 + d] = (acc - mean) * rstd * g[d] + be[d];
}

// ---------------- pos + pad outputs ----------------------------------------
__global__ void tail_kernel(const float* __restrict__ p4, float* __restrict__ out)
{
  const int t = threadIdx.x;
  if (t < 192) out[t] = p4[t];
  if (t < 64) out[192 + 24576 + t] = 0.0f;
}

// ---------------------------------------------------------------------------
extern "C" void kernel_launch(void* const* d_in, const int* in_sizes, int n_in,
                              void* d_out, int out_size, void* d_ws, size_t ws_size,
                              hipStream_t stream)
{
  (void)in_sizes; (void)n_in; (void)out_size; (void)ws_size;
  const float* pts    = (const float*)d_in[0];
  const float* lin_w  = (const float*)d_in[1];
  const float* lin_b  = (const float*)d_in[2];
  const float* src_w  = (const float*)d_in[3];
  const float* dst_w  = (const float*)d_in[4];
  const float* pos_w1 = (const float*)d_in[5];
  const float* pos_b1 = (const float*)d_in[6];
  const float* pos_w2 = (const float*)d_in[7];
  const float* pos_b2 = (const float*)d_in[8];
  const float* attn_w = (const float*)d_in[9];
  const float* attn_b = (const float*)d_in[10];
  const float* ln_g   = (const float*)d_in[11];
  const float* ln_b   = (const float*)d_in[12];
  const float* proj_w = (const float*)d_in[13];
  const float* proj_b = (const float*)d_in[14];
  const float* pln_g  = (const float*)d_in[15];
  const float* pln_b  = (const float*)d_in[16];
  float* out = (float*)d_out;

  // ---- workspace layout ----
  constexpr long SX0 = 4096L*384, SX1 = 1024L*384, SX2 = 256L*384, SX3 = 64L*384, SX4 = 16L*384;
  constexpr long SP0 = 4096L*3, SP1 = 1024L*3, SP2 = 256L*3, SP3 = 64L*3, SP4 = 16L*3;
  constexpr long SV  = 4096L*384;
  constexpr long SAD = 1024L*384;
  constexpr long SCH = 4096L*384;
  constexpr long SNB = 1024L*16;

  _Float16* wt = (_Float16*)d_ws;              // 20 matrices, 5.9 MB, 16B aligned
  float* ws = (float*)(wt + 20L * 147456);
  float* x0 = ws; ws += 4*SX0;
  float* x1 = ws; ws += 4*SX1;
  float* x2 = ws; ws += 4*SX2;
  float* x3 = ws; ws += 4*SX3;
  float* x4 = ws; ws += 4*SX4;
  float* p0 = ws; ws += 4*SP0;
  float* p1 = ws; ws += 4*SP1;
  float* p2 = ws; ws += 4*SP2;
  float* p3 = ws; ws += 4*SP3;
  float* p4 = ws; ws += 4*SP4;
  float* vb = ws; ws += 4*SV;
  float* asb = ws; ws += 4*SV;
  float* adb = ws; ws += 4*SAD;
  float* db = ws; ws += 4*SCH;
  float* ab = ws; ws += 4*SCH;
  float* vld = ws; ws += 4*SNB;
  int* nb = (int*)ws; ws += 4*SNB;
  int* ix[4];
  ix[0] = (int*)ws; ws += 4*1024;
  ix[1] = (int*)ws; ws += 4*256;
  ix[2] = (int*)ws; ws += 4*64;
  ix[3] = (int*)ws; ws += 4*16;

  const int Ns[4] = {4096, 1024, 256, 64};
  const int Ms[4] = {1024, 256, 64, 16};
  const double R2[4] = {1.0, 4.0, 16.0, 64.0};
  float* X[5] = {x0, x1, x2, x3, x4};
  float* P[5] = {p0, p1, p2, p3, p4};
  long SPs[5] = {SP0, SP1, SP2, SP3, SP4};
  long SXs[5] = {SX0, SX1, SX2, SX3, SX4};

  // split pts
  split_kernel<<<dim3(4096, 4), 128, 0, stream>>>(pts, p0, x0);

  // weight transpose + f16 (ids: lin=0..3, src=4..7, dst=8..11, posw2=12..15, attn=16..19)
  {
    TP tp{};
    tp.src[0] = lin_w; tp.src[1] = src_w; tp.src[2] = dst_w;
    tp.src[3] = pos_w2; tp.src[4] = attn_w;
    tp.dst = wt;
    transpose_kernel<<<dim3(12, 12, 20), 256, 0, stream>>>(tp);
  }

  // FPS chain
  fps_kernel<4096, 256><<<dim3(4), 256, 0, stream>>>(P[0], ix[0], P[1]);
  fps_kernel<1024, 256><<<dim3(4), 256, 0, stream>>>(P[1], ix[1], P[2]);
  fps_kernel<256, 64><<<dim3(4), 64, 0, stream>>>(P[2], ix[2], P[3]);
  fps_kernel<64, 64><<<dim3(4), 64, 0, stream>>>(P[3], ix[3], P[4]);

  for (int s = 0; s < 4; s++) {
    const int N = Ns[s], M = Ms[s];
    switch (s) {
      case 0: knn_kernel<64><<<dim3(M, 4), 64, 0, stream>>>(P[s], P[s+1], N, M, nb, vld, R2[s]); break;
      case 1: knn_kernel<16><<<dim3(M, 4), 64, 0, stream>>>(P[s], P[s+1], N, M, nb, vld, R2[s]); break;
      case 2: knn_kernel<4><<<dim3(M, 4), 64, 0, stream>>>(P[s], P[s+1], N, M, nb, vld, R2[s]); break;
      default: knn_kernel<1><<<dim3(M, 4), 64, 0, stream>>>(P[s], P[s+1], N, M, nb, vld, R2[s]); break;
    }
    // v = x@lw + lb
    {
      GemmP g{}; g.A = X[s]; g.sA = SXs[s]; g.Wt = wt + (long)(0*4+s)*147456; g.bias = lin_b + (long)s*384;
      g.C = vb; g.sC = SV; g.R = N;
      mgemm_kernel<0, false, true, false><<<dim3(N/64, 6, 4), 256, 0, stream>>>(g);
    }
    // a_src = x@sw
    {
      GemmP g{}; g.A = X[s]; g.sA = SXs[s]; g.Wt = wt + (long)(1*4+s)*147456;
      g.C = asb; g.sC = SV; g.R = N;
      mgemm_kernel<0, false, false, false><<<dim3(N/64, 6, 4), 256, 0, stream>>>(g);
    }
    // a_dst = x[idx]@dw
    {
      GemmP g{}; g.A = X[s]; g.sA = SXs[s]; g.Wt = wt + (long)(2*4+s)*147456;
      g.C = adb; g.sC = SAD; g.R = M; g.gather = ix[s]; g.sG = M;
      mgemm_kernel<0, true, false, false><<<dim3((M+63)/64, 6, 4), 256, 0, stream>>>(g);
    }
    // chunks of 256 queries: delta GEMM, alpha GEMM, softmax+LN
    const int nch = (M + 255) / 256;
    for (int c = 0; c < nch; c++) {
      const int q0 = c * 256;
      const int Mc = (M - q0 < 256) ? (M - q0) : 256;
      const int rows = Mc * 16;
      {
        GemmP g{}; g.Wt = wt + (long)(3*4+s)*147456; g.bias = pos_b2 + (long)s*384;
        g.C = db; g.sC = SCH; g.R = rows;
        g.qpos = P[s+1]; g.sQ = SPs[s+1]; g.pos = P[s]; g.sP = SPs[s];
        g.nbr = nb; g.sN = SNB; g.pw1 = pos_w1 + (long)s*1152; g.pb1 = pos_b1 + (long)s*384;
        g.row0 = q0 * 16;
        mgemm_kernel<1, false, true, true><<<dim3(rows/64, 6, 4), 256, 0, stream>>>(g);
      }
      {
        GemmP g{}; g.A = db; g.sA = SCH; g.Wt = wt + (long)(4*4+s)*147456; g.bias = attn_b + (long)s*384;
        g.C = ab; g.sC = SCH; g.R = rows;
        g.nbr = nb; g.sN = SNB; g.adst = adb; g.sAD = SAD; g.asrc = asb; g.sAS = SV;
        g.row0 = q0 * 16;
        mgemm_kernel<2, false, true, true><<<dim3(rows/64, 6, 4), 256, 0, stream>>>(g);
      }
      attnln_kernel<<<dim3(Mc, 4), 128, 0, stream>>>(
          ab, db, vb, nb, vld, ln_g + (long)s*384, ln_b + (long)s*384,
          X[s+1], q0, SCH, SV, SNB, (long)M*384);
    }
  }

  feat_kernel<<<dim3(16, 4), 384, 0, stream>>>(x4, proj_w, proj_b, pln_g, pln_b, out + 192);
  tail_kernel<<<1, 256, 0, stream>>>(p4, out);
}

// Round 5
// 1597.433 us; speedup vs baseline: 3.0317x; 1.5667x over previous
//
#include <hip/hip_runtime.h>
#include <math.h>

// ---------------------------------------------------------------------------
// GlobalSceneEncoder: 4-stage point-transformer encoder.
// FPS/KNN: bit-exact f32 replication of the numpy reference (no FMA,
// fixed summation order), u32/u64 monotone-key reductions.
// GEMMs: f16 MFMA w/ fp32 accum. Everything else fp32.
// B=4, N0=4096, D=384, K=16.
// ---------------------------------------------------------------------------

using half8 = __attribute__((ext_vector_type(8))) _Float16;
using f32x4 = __attribute__((ext_vector_type(4))) float;

__device__ __forceinline__ float d2f(float ax, float ay, float az,
                                     float bx, float by, float bz)
{
  // exact np order: ((dx*dx + dy*dy) + dz*dz), no contraction
  const float dx = __fsub_rn(ax, bx);
  const float dy = __fsub_rn(ay, by);
  const float dz = __fsub_rn(az, bz);
  return __fadd_rn(__fadd_rn(__fmul_rn(dx, dx), __fmul_rn(dy, dy)),
                   __fmul_rn(dz, dz));
}

// ---------------- split pts -> pos0, x0 ----------------
__global__ __launch_bounds__(128) void split_kernel(
    const float* __restrict__ pts, float* __restrict__ pos0, float* __restrict__ x0)
{
  const int n = blockIdx.x;
  const int b = blockIdx.y;
  const float* src = pts + ((long)b * 4096 + n) * 387;
  float* pd = pos0 + ((long)b * 4096 + n) * 3;
  float* xd = x0 + ((long)b * 4096 + n) * 384;
  for (int e = threadIdx.x; e < 387; e += 128) {
    float v = src[e];
    if (e < 3) pd[e] = v; else xd[e - 3] = v;
  }
}

// ---------------- weight transpose + f16 convert: Wt[n][k] = W[k][n] -------
struct TP { const float* src[5]; _Float16* dst; };
__global__ __launch_bounds__(256) void transpose_kernel(TP p)
{
  const int z = blockIdx.z;
  const float* S = p.src[z >> 2] + (long)(z & 3) * 147456;
  _Float16* Dst = p.dst + (long)z * 147456;
  const int k0 = blockIdx.x * 32, n0 = blockIdx.y * 32;
  __shared__ float tile[32][33];
  const int ti = threadIdx.x & 31, tj = threadIdx.x >> 5;
  #pragma unroll
  for (int p8 = 0; p8 < 32; p8 += 8)
    tile[tj + p8][ti] = S[(long)(k0 + tj + p8) * 384 + n0 + ti];
  __syncthreads();
  #pragma unroll
  for (int p8 = 0; p8 < 32; p8 += 8)
    Dst[(long)(n0 + tj + p8) * 384 + k0 + ti] = (_Float16)tile[ti][tj + p8];
}

// ---------------- FPS v4: f32 exact, u32-key butterfly, ballot index -------
// Contiguous ownership: thread t owns points [t*NPT, (t+1)*NPT) so
// lowest-lane tie-break == lowest-index tie-break.
template<int NPTS, int NTHR>
__global__ __launch_bounds__(NTHR, 1) void fps_kernel(
    const float* __restrict__ pos,
    int* __restrict__ idx_out, float* __restrict__ pos_out)
{
  constexpr int NPT = NPTS / NTHR;
  constexpr int NW = NTHR / 64;
  constexpr int M = NPTS / 4;
  const int b = blockIdx.x;
  pos += (long)b * NPTS * 3; idx_out += (long)b * M; pos_out += (long)b * M * 3;
  const int t = threadIdx.x;

  __shared__ float spx[NPTS], spy[NPTS], spz[NPTS];
  __shared__ unsigned long long s_key[2][NW > 1 ? NW : 1];

  float px[NPT], py[NPT], pz[NPT], dmin[NPT];
  #pragma unroll
  for (int i = 0; i < NPT; i++) {
    const int j = t * NPT + i;
    px[i] = pos[j*3]; py[i] = pos[j*3+1]; pz[i] = pos[j*3+2];
    spx[j] = px[i]; spy[j] = py[i]; spz[j] = pz[i];
  }
  const float sx = pos[0], sy = pos[1], sz = pos[2];
  #pragma unroll
  for (int i = 0; i < NPT; i++)
    dmin[i] = d2f(px[i], py[i], pz[i], sx, sy, sz);
  if (t == 0) { idx_out[0] = 0; pos_out[0] = sx; pos_out[1] = sy; pos_out[2] = sz; }
  if (NW > 1) __syncthreads();   // spx/spy/spz visible

  for (int m = 1; m < M; ++m) {
    // ---- local argmax, log-depth tree (strict > keeps lower i on ties) ----
    float bv[NPT]; int bi[NPT];
    #pragma unroll
    for (int i = 0; i < NPT; i++) { bv[i] = dmin[i]; bi[i] = i; }
    #pragma unroll
    for (int st = NPT > 1 ? NPT >> 1 : 0; st >= 1; st >>= 1)
      #pragma unroll
      for (int i = 0; i < st; i++)
        if (bv[i + st] > bv[i]) { bv[i] = bv[i + st]; bi[i] = bi[i + st]; }
    const unsigned myub = __float_as_uint(bv[0]);     // dmin >= 0 -> monotone
    const int myj = t * NPT + bi[0];
    // ---- wave max butterfly on u32 key ----
    unsigned ub = myub;
    #pragma unroll
    for (int off = 32; off; off >>= 1) {
      const unsigned o = __shfl_xor(ub, off);
      ub = o > ub ? o : ub;
    }
    // ---- lowest lane holding the max -> wave winner index ----
    const unsigned long long mk = __ballot(myub == ub);
    const int srclane = __builtin_ctzll(mk);
    const int wj = __shfl(myj, srclane);

    int sel;
    if (NW > 1) {
      const int p = m & 1;
      const unsigned long long key =
          ((unsigned long long)ub << 32) | (unsigned)(NPTS - 1 - wj);
      if ((t & 63) == 0) s_key[p][t >> 6] = key;
      __syncthreads();
      unsigned long long kb = s_key[p][0];
      #pragma unroll
      for (int w2 = 1; w2 < NW; w2++) {
        const unsigned long long o = s_key[p][w2];
        if (o > kb) kb = o;
      }
      sel = NPTS - 1 - (int)(kb & 0xFFFFFFFFu);
    } else {
      sel = wj;
    }
    // ---- broadcast position lookup + exact-f32 update ----
    const float qx = spx[sel], qy = spy[sel], qz = spz[sel];
    #pragma unroll
    for (int i = 0; i < NPT; i++) {
      const float dd = d2f(px[i], py[i], pz[i], qx, qy, qz);
      dmin[i] = fminf(dmin[i], dd);
    }
    if (t == 0) { idx_out[m] = sel; pos_out[m*3] = qx; pos_out[m*3+1] = qy; pos_out[m*3+2] = qz; }
  }
}

// ---------------- KNN: one wave/query, 16 passes, u64 (dist,j) keys --------
template<int C>
__global__ __launch_bounds__(64) void knn_kernel(
    const float* __restrict__ pos, const float* __restrict__ qpos,
    int N, int M, int* __restrict__ nbr, float* __restrict__ vld, float r2)
{
  const int m = blockIdx.x, b = blockIdx.y;
  pos += (long)b * N * 3; qpos += (long)b * M * 3;
  nbr += (long)b * (1024 * 16); vld += (long)b * (1024 * 16);
  const int lane = threadIdx.x;
  const float qx = qpos[m*3], qy = qpos[m*3+1], qz = qpos[m*3+2];
  unsigned long long key[C];
  #pragma unroll
  for (int c = 0; c < C; c++) {
    const int j = c * 64 + lane;
    const float dd = d2f(pos[j*3], pos[j*3+1], pos[j*3+2], qx, qy, qz);
    key[c] = ((unsigned long long)__float_as_uint(dd) << 32) | (unsigned)j;
  }
  unsigned long long prev = 0;
  for (int k = 0; k < 16; k++) {
    unsigned long long best = ~0ull;
    #pragma unroll
    for (int c = 0; c < C; c++) {
      const bool take = (k == 0) || (key[c] > prev);
      if (take && key[c] < best) best = key[c];
    }
    #pragma unroll
    for (int off = 32; off; off >>= 1) {
      const unsigned long long o = __shfl_xor(best, off);
      if (o < best) best = o;
    }
    prev = best;
    if (lane == 0) {
      nbr[m*16+k] = (int)(best & 0xFFFFFFFFu);
      const float dd = __uint_as_float((unsigned)(best >> 32));
      vld[m*16+k] = (dd <= r2) ? 1.0f : 0.0f;
    }
  }
}

// ---------------- f16 MFMA GEMM, 64x64 tile, BK=32, 3 A-operand modes ------
struct GemmP {
  const float* A; long sA;
  const _Float16* Wt;          // pre-transposed f16 weights: Wt[n][k]
  const float* bias;
  float* C; long sC;
  int R;
  const int* gather; long sG;
  const float* qpos; long sQ;
  const float* pos;  long sP;
  const int* nbr;    long sN;
  const float* pw1;
  const float* pb1;
  const float* adst; long sAD;
  const float* asrc; long sAS;
  int row0;
};

template<int AMODE, bool GATHER, bool BIAS, bool RELU>
__global__ __launch_bounds__(256) void mgemm_kernel(GemmP p)
{
  const int b = blockIdx.z;
  const int rb = blockIdx.x * 64;
  const int cb = blockIdx.y * 64;
  const int t = threadIdx.x;
  const float* A = p.A ? (p.A + (long)b * p.sA) : nullptr;
  float* C = p.C + (long)b * p.sC;
  const int* gat = GATHER ? (p.gather + (long)b * p.sG) : nullptr;
  const int* nbrb = (AMODE != 0) ? (p.nbr + (long)b * p.sN) : nullptr;

  __shared__ _Float16 As[64][40];
  __shared__ _Float16 Bs[64][40];

  const int w = t >> 6, lane = t & 63;
  const int wm = w & 1, wn = w >> 1;
  const int quad = lane >> 4, l16 = lane & 15;

  f32x4 acc[2][2] = {};

  const int sr = t >> 2;
  const int sk = (t & 3) << 3;
  const int ar = rb + sr;

  const float* arow = nullptr;
  const float* adrow = nullptr;
  const float* asrow = nullptr;
  bool avalid = true;
  float rx = 0.f, ry = 0.f, rz = 0.f;
  if (AMODE == 0) {
    avalid = (ar < p.R);
    long srcrow = 0;
    if (avalid) srcrow = GATHER ? (long)gat[ar] : (long)ar;
    arow = A + srcrow * 384;
  } else {
    const int grow = p.row0 + ar;
    const int mq = grow >> 4;
    const int n = nbrb[grow];
    if (AMODE == 1) {
      const float* qposb = p.qpos + (long)b * p.sQ;
      const float* posb = p.pos + (long)b * p.sP;
      rx = qposb[mq*3+0] - posb[n*3+0];
      ry = qposb[mq*3+1] - posb[n*3+1];
      rz = qposb[mq*3+2] - posb[n*3+2];
    } else {
      arow = A + (long)ar * 384;
      adrow = p.adst + (long)b * p.sAD + (long)mq * 384;
      asrow = p.asrc + (long)b * p.sAS + (long)n * 384;
    }
  }

  for (int k0 = 0; k0 < 384; k0 += 32) {
    float a8[8];
    if (AMODE == 0) {
      if (avalid) {
        const float4 u = *(const float4*)(arow + k0 + sk);
        const float4 v = *(const float4*)(arow + k0 + sk + 4);
        a8[0]=u.x; a8[1]=u.y; a8[2]=u.z; a8[3]=u.w;
        a8[4]=v.x; a8[5]=v.y; a8[6]=v.z; a8[7]=v.w;
      } else {
        #pragma unroll
        for (int j = 0; j < 8; j++) a8[j] = 0.f;
      }
    } else if (AMODE == 1) {
      const int kc = k0 + sk;
      const float4 w0a = *(const float4*)(p.pw1 + kc);
      const float4 w0b = *(const float4*)(p.pw1 + kc + 4);
      const float4 w1a = *(const float4*)(p.pw1 + 384 + kc);
      const float4 w1b = *(const float4*)(p.pw1 + 384 + kc + 4);
      const float4 w2a = *(const float4*)(p.pw1 + 768 + kc);
      const float4 w2b = *(const float4*)(p.pw1 + 768 + kc + 4);
      const float4 b1a = *(const float4*)(p.pb1 + kc);
      const float4 b1b = *(const float4*)(p.pb1 + kc + 4);
      a8[0] = fmaxf(rx*w0a.x + ry*w1a.x + rz*w2a.x + b1a.x, 0.f);
      a8[1] = fmaxf(rx*w0a.y + ry*w1a.y + rz*w2a.y + b1a.y, 0.f);
      a8[2] = fmaxf(rx*w0a.z + ry*w1a.z + rz*w2a.z + b1a.z, 0.f);
      a8[3] = fmaxf(rx*w0a.w + ry*w1a.w + rz*w2a.w + b1a.w, 0.f);
      a8[4] = fmaxf(rx*w0b.x + ry*w1b.x + rz*w2b.x + b1b.x, 0.f);
      a8[5] = fmaxf(rx*w0b.y + ry*w1b.y + rz*w2b.y + b1b.y, 0.f);
      a8[6] = fmaxf(rx*w0b.z + ry*w1b.z + rz*w2b.z + b1b.z, 0.f);
      a8[7] = fmaxf(rx*w0b.w + ry*w1b.w + rz*w2b.w + b1b.w, 0.f);
    } else {
      const int kc = k0 + sk;
      const float4 d0 = *(const float4*)(arow + kc);
      const float4 d1 = *(const float4*)(arow + kc + 4);
      const float4 a0 = *(const float4*)(adrow + kc);
      const float4 a1 = *(const float4*)(adrow + kc + 4);
      const float4 s0 = *(const float4*)(asrow + kc);
      const float4 s1 = *(const float4*)(asrow + kc + 4);
      a8[0] = a0.x - s0.x + d0.x; a8[1] = a0.y - s0.y + d0.y;
      a8[2] = a0.z - s0.z + d0.z; a8[3] = a0.w - s0.w + d0.w;
      a8[4] = a1.x - s1.x + d1.x; a8[5] = a1.y - s1.y + d1.y;
      a8[6] = a1.z - s1.z + d1.z; a8[7] = a1.w - s1.w + d1.w;
    }
    const half8 bv = *(const half8*)(p.Wt + (long)(cb + sr) * 384 + k0 + sk);

    __syncthreads();
    half8 av;
    #pragma unroll
    for (int j = 0; j < 8; j++) av[j] = (_Float16)a8[j];
    *(half8*)&As[sr][sk] = av;
    *(half8*)&Bs[sr][sk] = bv;
    __syncthreads();

    const half8 fa0 = *(const half8*)&As[wm*32 + l16][quad*8];
    const half8 fa1 = *(const half8*)&As[wm*32 + 16 + l16][quad*8];
    const half8 fb0 = *(const half8*)&Bs[wn*32 + l16][quad*8];
    const half8 fb1 = *(const half8*)&Bs[wn*32 + 16 + l16][quad*8];
    acc[0][0] = __builtin_amdgcn_mfma_f32_16x16x32_f16(fa0, fb0, acc[0][0], 0, 0, 0);
    acc[0][1] = __builtin_amdgcn_mfma_f32_16x16x32_f16(fa0, fb1, acc[0][1], 0, 0, 0);
    acc[1][0] = __builtin_amdgcn_mfma_f32_16x16x32_f16(fa1, fb0, acc[1][0], 0, 0, 0);
    acc[1][1] = __builtin_amdgcn_mfma_f32_16x16x32_f16(fa1, fb1, acc[1][1], 0, 0, 0);
  }

  float bi0 = 0.f, bi1 = 0.f;
  if (BIAS) {
    bi0 = p.bias[cb + wn*32 + l16];
    bi1 = p.bias[cb + wn*32 + 16 + l16];
  }
  #pragma unroll
  for (int i = 0; i < 2; i++) {
    const int base = rb + wm*32 + i*16;
    if (base < p.R) {
      const int r0 = base + quad*4;
      #pragma unroll
      for (int j = 0; j < 2; j++) {
        const int col = cb + wn*32 + j*16 + l16;
        const float bb = j ? bi1 : bi0;
        #pragma unroll
        for (int reg = 0; reg < 4; reg++) {
          float v = acc[i][j][reg] + bb;
          if (RELU) v = fmaxf(v, 0.f);
          C[(long)(r0 + reg) * 384 + col] = v;
        }
      }
    }
  }
}

// ---------------- masked softmax over K + weighted sum + LayerNorm ---------
__global__ __launch_bounds__(128) void attnln_kernel(
    const float* __restrict__ alpha, const float* __restrict__ delta,
    const float* __restrict__ vbuf, const int* __restrict__ nbr,
    const float* __restrict__ vldb, const float* __restrict__ lng,
    const float* __restrict__ lnb, float* __restrict__ xout,
    int q0, long sCh, long sV, long sNb, long sX)
{
  const int ml = blockIdx.x, b = blockIdx.y;
  const int m = q0 + ml;
  alpha += (long)b * sCh; delta += (long)b * sCh; vbuf += (long)b * sV;
  nbr += (long)b * sNb; vldb += (long)b * sNb; xout += (long)b * sX;
  const int t = threadIdx.x;

  int nb[16]; float vl[16];
  #pragma unroll
  for (int k = 0; k < 16; k++) { nb[k] = nbr[m*16+k]; vl[k] = vldb[m*16+k]; }

  const long rbase = (long)ml * 16 * 384;
  float av[16][3];
  #pragma unroll
  for (int k = 0; k < 16; k++)
    #pragma unroll
    for (int i = 0; i < 3; i++) {
      const float a = alpha[rbase + k*384 + t + i*128];
      av[k][i] = (vl[k] > 0.5f) ? a : -1e30f;
    }
  float mx[3] = {-3.4e38f, -3.4e38f, -3.4e38f};
  #pragma unroll
  for (int k = 0; k < 16; k++)
    #pragma unroll
    for (int i = 0; i < 3; i++) mx[i] = fmaxf(mx[i], av[k][i]);
  float sm[3] = {0.f, 0.f, 0.f};
  #pragma unroll
  for (int k = 0; k < 16; k++)
    #pragma unroll
    for (int i = 0; i < 3; i++) { const float e = expf(av[k][i] - mx[i]); av[k][i] = e; sm[i] += e; }
  float rs[3];
  #pragma unroll
  for (int i = 0; i < 3; i++) rs[i] = 1.0f / sm[i];
  float o[3] = {0.f, 0.f, 0.f};
  #pragma unroll
  for (int k = 0; k < 16; k++) {
    const long nrow = (long)nb[k] * 384;
    #pragma unroll
    for (int i = 0; i < 3; i++) {
      const int dd = t + i * 128;
      const float vv = vbuf[nrow + dd] + delta[rbase + k*384 + dd];
      o[i] += (av[k][i] * rs[i] * vl[k]) * vv;
    }
  }
  __shared__ float sred[2];
  float s1 = o[0] + o[1] + o[2];
  #pragma unroll
  for (int off = 32; off; off >>= 1) s1 += __shfl_xor(s1, off);
  if ((t & 63) == 0) sred[t >> 6] = s1;
  __syncthreads();
  const float mean = (sred[0] + sred[1]) * (1.0f / 384.0f);
  __syncthreads();
  float s2 = 0.f;
  #pragma unroll
  for (int i = 0; i < 3; i++) { const float dd = o[i] - mean; s2 += dd * dd; }
  #pragma unroll
  for (int off = 32; off; off >>= 1) s2 += __shfl_xor(s2, off);
  if ((t & 63) == 0) sred[t >> 6] = s2;
  __syncthreads();
  const float var = (sred[0] + sred[1]) * (1.0f / 384.0f);
  const float rstd = 1.0f / sqrtf(var + 1e-5f);
  #pragma unroll
  for (int i = 0; i < 3; i++) {
    const int dd = t + i * 128;
    xout[(long)m * 384 + dd] = (o[i] - mean) * rstd * lng[dd] + lnb[dd];
  }
}

// ---------------- final projection + LayerNorm -----------------------------
__global__ __launch_bounds__(384) void feat_kernel(
    const float* __restrict__ x4, const float* __restrict__ pw,
    const float* __restrict__ pb, const float* __restrict__ g,
    const float* __restrict__ be, float* __restrict__ outf)
{
  const int row = blockIdx.x, b = blockIdx.y;
  const long r = (long)b * 16 + row;
  const int d = threadIdx.x;
  __shared__ float xs[384];
  xs[d] = x4[r * 384 + d];
  __syncthreads();
  float acc = pb[d];
  #pragma unroll 8
  for (int j = 0; j < 384; j++) acc = fmaf(xs[j], pw[(long)j * 384 + d], acc);
  __shared__ float sred[6];
  float s = acc;
  #pragma unroll
  for (int off = 32; off; off >>= 1) s += __shfl_xor(s, off);
  if ((d & 63) == 0) sred[d >> 6] = s;
  __syncthreads();
  const float mean = (sred[0]+sred[1]+sred[2]+sred[3]+sred[4]+sred[5]) * (1.0f/384.0f);
  __syncthreads();
  float dv = (acc - mean) * (acc - mean);
  #pragma unroll
  for (int off = 32; off; off >>= 1) dv += __shfl_xor(dv, off);
  if ((d & 63) == 0) sred[d >> 6] = dv;
  __syncthreads();
  const float var = (sred[0]+sred[1]+sred[2]+sred[3]+sred[4]+sred[5]) * (1.0f/384.0f);
  const float rstd = 1.0f / sqrtf(var + 1e-5f);
  outf[r * 384 + d] = (acc - mean) * rstd * g[d] + be[d];
}

// ---------------- pos + pad outputs ----------------------------------------
__global__ void tail_kernel(const float* __restrict__ p4, float* __restrict__ out)
{
  const int t = threadIdx.x;
  if (t < 192) out[t] = p4[t];
  if (t < 64) out[192 + 24576 + t] = 0.0f;
}

// ---------------------------------------------------------------------------
extern "C" void kernel_launch(void* const* d_in, const int* in_sizes, int n_in,
                              void* d_out, int out_size, void* d_ws, size_t ws_size,
                              hipStream_t stream)
{
  (void)in_sizes; (void)n_in; (void)out_size; (void)ws_size;
  const float* pts    = (const float*)d_in[0];
  const float* lin_w  = (const float*)d_in[1];
  const float* lin_b  = (const float*)d_in[2];
  const float* src_w  = (const float*)d_in[3];
  const float* dst_w  = (const float*)d_in[4];
  const float* pos_w1 = (const float*)d_in[5];
  const float* pos_b1 = (const float*)d_in[6];
  const float* pos_w2 = (const float*)d_in[7];
  const float* pos_b2 = (const float*)d_in[8];
  const float* attn_w = (const float*)d_in[9];
  const float* attn_b = (const float*)d_in[10];
  const float* ln_g   = (const float*)d_in[11];
  const float* ln_b   = (const float*)d_in[12];
  const float* proj_w = (const float*)d_in[13];
  const float* proj_b = (const float*)d_in[14];
  const float* pln_g  = (const float*)d_in[15];
  const float* pln_b  = (const float*)d_in[16];
  float* out = (float*)d_out;

  // ---- workspace layout ----
  constexpr long SX0 = 4096L*384, SX1 = 1024L*384, SX2 = 256L*384, SX3 = 64L*384, SX4 = 16L*384;
  constexpr long SP0 = 4096L*3, SP1 = 1024L*3, SP2 = 256L*3, SP3 = 64L*3, SP4 = 16L*3;
  constexpr long SV  = 4096L*384;
  constexpr long SAD = 1024L*384;
  constexpr long SCH = 4096L*384;
  constexpr long SNB = 1024L*16;

  _Float16* wt = (_Float16*)d_ws;
  float* ws = (float*)(wt + 20L * 147456);
  float* x0 = ws; ws += 4*SX0;
  float* x1 = ws; ws += 4*SX1;
  float* x2 = ws; ws += 4*SX2;
  float* x3 = ws; ws += 4*SX3;
  float* x4 = ws; ws += 4*SX4;
  float* p0 = ws; ws += 4*SP0;
  float* p1 = ws; ws += 4*SP1;
  float* p2 = ws; ws += 4*SP2;
  float* p3 = ws; ws += 4*SP3;
  float* p4 = ws; ws += 4*SP4;
  float* vb = ws; ws += 4*SV;
  float* asb = ws; ws += 4*SV;
  float* adb = ws; ws += 4*SAD;
  float* db = ws; ws += 4*SCH;
  float* ab = ws; ws += 4*SCH;
  float* vld = ws; ws += 4*SNB;
  int* nb = (int*)ws; ws += 4*SNB;
  int* ix[4];
  ix[0] = (int*)ws; ws += 4*1024;
  ix[1] = (int*)ws; ws += 4*256;
  ix[2] = (int*)ws; ws += 4*64;
  ix[3] = (int*)ws; ws += 4*16;

  const int Ns[4] = {4096, 1024, 256, 64};
  const int Ms[4] = {1024, 256, 64, 16};
  const float R2[4] = {1.0f, 4.0f, 16.0f, 64.0f};
  float* X[5] = {x0, x1, x2, x3, x4};
  float* P[5] = {p0, p1, p2, p3, p4};
  long SPs[5] = {SP0, SP1, SP2, SP3, SP4};
  long SXs[5] = {SX0, SX1, SX2, SX3, SX4};

  split_kernel<<<dim3(4096, 4), 128, 0, stream>>>(pts, p0, x0);

  {
    TP tp{};
    tp.src[0] = lin_w; tp.src[1] = src_w; tp.src[2] = dst_w;
    tp.src[3] = pos_w2; tp.src[4] = attn_w;
    tp.dst = wt;
    transpose_kernel<<<dim3(12, 12, 20), 256, 0, stream>>>(tp);
  }

  // FPS chain
  fps_kernel<4096, 256><<<dim3(4), 256, 0, stream>>>(P[0], ix[0], P[1]);
  fps_kernel<1024, 256><<<dim3(4), 256, 0, stream>>>(P[1], ix[1], P[2]);
  fps_kernel<256, 64><<<dim3(4), 64, 0, stream>>>(P[2], ix[2], P[3]);
  fps_kernel<64, 64><<<dim3(4), 64, 0, stream>>>(P[3], ix[3], P[4]);

  for (int s = 0; s < 4; s++) {
    const int N = Ns[s], M = Ms[s];
    switch (s) {
      case 0: knn_kernel<64><<<dim3(M, 4), 64, 0, stream>>>(P[s], P[s+1], N, M, nb, vld, R2[s]); break;
      case 1: knn_kernel<16><<<dim3(M, 4), 64, 0, stream>>>(P[s], P[s+1], N, M, nb, vld, R2[s]); break;
      case 2: knn_kernel<4><<<dim3(M, 4), 64, 0, stream>>>(P[s], P[s+1], N, M, nb, vld, R2[s]); break;
      default: knn_kernel<1><<<dim3(M, 4), 64, 0, stream>>>(P[s], P[s+1], N, M, nb, vld, R2[s]); break;
    }
    // v = x@lw + lb
    {
      GemmP g{}; g.A = X[s]; g.sA = SXs[s]; g.Wt = wt + (long)(0*4+s)*147456; g.bias = lin_b + (long)s*384;
      g.C = vb; g.sC = SV; g.R = N;
      mgemm_kernel<0, false, true, false><<<dim3(N/64, 6, 4), 256, 0, stream>>>(g);
    }
    // a_src = x@sw
    {
      GemmP g{}; g.A = X[s]; g.sA = SXs[s]; g.Wt = wt + (long)(1*4+s)*147456;
      g.C = asb; g.sC = SV; g.R = N;
      mgemm_kernel<0, false, false, false><<<dim3(N/64, 6, 4), 256, 0, stream>>>(g);
    }
    // a_dst = x[idx]@dw
    {
      GemmP g{}; g.A = X[s]; g.sA = SXs[s]; g.Wt = wt + (long)(2*4+s)*147456;
      g.C = adb; g.sC = SAD; g.R = M; g.gather = ix[s]; g.sG = M;
      mgemm_kernel<0, true, false, false><<<dim3((M+63)/64, 6, 4), 256, 0, stream>>>(g);
    }
    const int nch = (M + 255) / 256;
    for (int c = 0; c < nch; c++) {
      const int q0 = c * 256;
      const int Mc = (M - q0 < 256) ? (M - q0) : 256;
      const int rows = Mc * 16;
      {
        GemmP g{}; g.Wt = wt + (long)(3*4+s)*147456; g.bias = pos_b2 + (long)s*384;
        g.C = db; g.sC = SCH; g.R = rows;
        g.qpos = P[s+1]; g.sQ = SPs[s+1]; g.pos = P[s]; g.sP = SPs[s];
        g.nbr = nb; g.sN = SNB; g.pw1 = pos_w1 + (long)s*1152; g.pb1 = pos_b1 + (long)s*384;
        g.row0 = q0 * 16;
        mgemm_kernel<1, false, true, true><<<dim3(rows/64, 6, 4), 256, 0, stream>>>(g);
      }
      {
        GemmP g{}; g.A = db; g.sA = SCH; g.Wt = wt + (long)(4*4+s)*147456; g.bias = attn_b + (long)s*384;
        g.C = ab; g.sC = SCH; g.R = rows;
        g.nbr = nb; g.sN = SNB; g.adst = adb; g.sAD = SAD; g.asrc = asb; g.sAS = SV;
        g.row0 = q0 * 16;
        mgemm_kernel<2, false, true, true><<<dim3(rows/64, 6, 4), 256, 0, stream>>>(g);
      }
      attnln_kernel<<<dim3(Mc, 4), 128, 0, stream>>>(
          ab, db, vb, nb, vld, ln_g + (long)s*384, ln_b + (long)s*384,
          X[s+1], q0, SCH, SV, SNB, (long)M*384);
    }
  }

  feat_kernel<<<dim3(16, 4), 384, 0, stream>>>(x4, proj_w, proj_b, pln_g, pln_b, out + 192);
  tail_kernel<<<1, 256, 0, stream>>>(p4, out);
}